// Round 1
// baseline (9288.963 us; speedup 1.0000x reference)
//
#include <hip/hip_runtime.h>
#include <hip/hip_bf16.h>
#include <cstddef>

#define CDIV(a,b) (((a)+(b)-1)/(b))

static constexpr float BN_EPS = 1e-5f;

// ---------------- generic small-weight GEMM: C[N,M] = A[N,K] @ W ----------------
// W is [K,M] (TRANSW=false) or [M,K] accessed transposed (TRANSW=true).
template<int K, int M, int TM, bool TRANSW>
__global__ __launch_bounds__(256) void gemm_k(const float* __restrict__ A,
                                              const float* __restrict__ W,
                                              float* __restrict__ C, int N) {
  constexpr int ROWS = 256 * TM / M;   // rows per block
  constexpr int CGS  = M / TM;         // threads per row
  __shared__ float Ws[K * M];
  __shared__ float As[ROWS * (K + 1)];
  for (int i = threadIdx.x; i < K * M; i += 256) {
    int k = i / M, m = i - k * M;
    Ws[i] = TRANSW ? W[m * K + k] : W[i];
  }
  int row0 = blockIdx.x * ROWS;
  for (int i = threadIdx.x; i < ROWS * K; i += 256) {
    int r = i / K, k = i - r * K;
    int row = row0 + r;
    As[r * (K + 1) + k] = (row < N) ? A[(size_t)row * K + k] : 0.f;
  }
  __syncthreads();
  const int cg = threadIdx.x % CGS;
  const int r  = threadIdx.x / CGS;
  float acc[TM];
#pragma unroll
  for (int j = 0; j < TM; ++j) acc[j] = 0.f;
  const float* as = &As[r * (K + 1)];
  const float* ws = &Ws[cg * TM];
#pragma unroll 4
  for (int k = 0; k < K; ++k) {
    float a = as[k];
#pragma unroll
    for (int j = 0; j < TM; ++j) acc[j] += a * ws[k * M + j];
  }
  int row = row0 + r;
  if (row < N) {
#pragma unroll
    for (int j = 0; j < TM; ++j) C[(size_t)row * M + cg * TM + j] = acc[j];
  }
}

// ---------------- column stats (sum, sumsq) over [N,M] ----------------
template<int M>
__global__ __launch_bounds__(256) void stats_k(const float* __restrict__ X,
                                               float* __restrict__ s, float* __restrict__ q,
                                               int N) {
  __shared__ float ls[M], lq[M];
  for (int i = threadIdx.x; i < M; i += 256) { ls[i] = 0.f; lq[i] = 0.f; }
  __syncthreads();
  size_t total = (size_t)N * M;
  for (size_t i = (size_t)blockIdx.x * 256 + threadIdx.x; i < total; i += (size_t)gridDim.x * 256) {
    float v = X[i];
    int c = (int)(i % M);
    atomicAdd(&ls[c], v);
    atomicAdd(&lq[c], v * v);
  }
  __syncthreads();
  for (int i = threadIdx.x; i < M; i += 256) {
    atomicAdd(&s[i], ls[i]);
    atomicAdd(&q[i], lq[i]);
  }
}

// ---------------- BN(train-stats) + ReLU, optional residual add into Y ----------------
__global__ __launch_bounds__(256) void bnrelu_k(const float* __restrict__ X, float* __restrict__ Y,
                                                const float* __restrict__ s, const float* __restrict__ q,
                                                const float* __restrict__ g, const float* __restrict__ be,
                                                int N, int M, int residual) {
  size_t i = (size_t)blockIdx.x * 256 + threadIdx.x;
  if (i >= (size_t)N * M) return;
  int c = (int)(i % M);
  float invN = 1.f / (float)N;
  float mean = s[c] * invN;
  float var  = fmaxf(q[c] * invN - mean * mean, 0.f);
  float sc   = g[c] * rsqrtf(var + BN_EPS);
  float v    = (X[i] - mean) * sc + be[c];
  v = fmaxf(v, 0.f);
  if (residual) Y[i] += v; else Y[i] = v;
}

// ---------------- graph prep ----------------
__global__ void fill_k(float* p, float v, int n) {
  int i = blockIdx.x * 256 + threadIdx.x;
  if (i < n) p[i] = v;
}
__global__ void deg_k(const int* __restrict__ dst, const float* __restrict__ w,
                      float* __restrict__ deg, int E) {
  int e = blockIdx.x * 256 + threadIdx.x;
  if (e < E) atomicAdd(&deg[dst[e]], w[e]);
}
__global__ void rsqrt_k(float* p, int n) {
  int i = blockIdx.x * 256 + threadIdx.x;
  if (i < n) p[i] = rsqrtf(p[i]);   // deg >= 1 always (self loop)
}
__global__ void hist_k(const int* __restrict__ dst, int* __restrict__ cnt, int E) {
  int e = blockIdx.x * 256 + threadIdx.x;
  if (e < E) atomicAdd(&cnt[dst[e]], 1);
}
// block-level inclusive scan (writes inclusive sums + per-block totals)
__global__ __launch_bounds__(256) void scan_block(const int* __restrict__ in, int n,
                                                  int* __restrict__ incl, int* __restrict__ bsum) {
  int i = blockIdx.x * 256 + threadIdx.x;
  int v = (i < n) ? in[i] : 0;
  int lane = threadIdx.x & 63;
  int sidx = threadIdx.x >> 6;
  int sv = v;
  for (int off = 1; off < 64; off <<= 1) {
    int t = __shfl_up(sv, off, 64);
    if (lane >= off) sv += t;
  }
  __shared__ int wsum[4];
  if (lane == 63) wsum[sidx] = sv;
  __syncthreads();
  int add = 0;
  for (int w = 0; w < sidx; ++w) add += wsum[w];
  sv += add;
  if (i < n) incl[i] = sv;
  if (threadIdx.x == 255 && bsum) bsum[blockIdx.x] = sv;
}
__global__ void scan3_k(const int* __restrict__ incl, const int* __restrict__ cnt,
                        const int* __restrict__ bincl, int* __restrict__ rowptr, int n, int E) {
  int i = blockIdx.x * 256 + threadIdx.x;
  if (i < n) rowptr[i] = incl[i] - cnt[i] + (blockIdx.x ? bincl[blockIdx.x - 1] : 0);
  if (i == 0) rowptr[n] = E;
}
__global__ void copy_k(const int* a, int* b, int n) {
  int i = blockIdx.x * 256 + threadIdx.x;
  if (i < n) b[i] = a[i];
}
__global__ void scatter_k(const int* __restrict__ src, const int* __restrict__ dst,
                          const float* __restrict__ w, const float* __restrict__ dinv,
                          int* __restrict__ cursor, int* __restrict__ eidx,
                          float* __restrict__ enorm, int E) {
  int e = blockIdx.x * 256 + threadIdx.x;
  if (e >= E) return;
  int d = dst[e], s2 = src[e];
  int pos = atomicAdd(&cursor[d], 1);
  eidx[pos] = s2;
  enorm[pos] = dinv[s2] * w[e] * dinv[d];
}

// ---------------- GCN aggregation: one wave per node, lane = feature ----------------
__global__ __launch_bounds__(256) void agg_k(const float* __restrict__ xw, const float* __restrict__ dinv,
                                             const int* __restrict__ rowptr, const int* __restrict__ eidx,
                                             const float* __restrict__ enorm, float* __restrict__ agg, int N) {
  int wv = (blockIdx.x * 256 + threadIdx.x) >> 6;
  int f  = threadIdx.x & 63;
  if (wv >= N) return;
  float di = dinv[wv];
  float acc = xw[(size_t)wv * 64 + f] * di * di;   // self loop (weight 1)
  int b = rowptr[wv], e = rowptr[wv + 1];
  for (int j = b; j < e; ++j) {
    acc += xw[(size_t)eidx[j] * 64 + f] * enorm[j];
  }
  agg[(size_t)wv * 64 + f] = acc;
}

// ---------------- GRU gate fusion ----------------
__global__ __launch_bounds__(256) void gru_gate_k(const float* __restrict__ gi, const float* __restrict__ gh,
                                                  const float* __restrict__ bih, const float* __restrict__ bhh,
                                                  const float* __restrict__ hprev, float* __restrict__ hnext, int N) {
  int idx = blockIdx.x * 256 + threadIdx.x;
  if (idx >= N * 64) return;
  int n = idx >> 6, j = idx & 63;
  const float* gin = gi + (size_t)n * 192;
  const float* ghn = gh + (size_t)n * 192;
  float ir = gin[j]       + bih[j],       hr = ghn[j]       + bhh[j];
  float iz = gin[64 + j]  + bih[64 + j],  hz = ghn[64 + j]  + bhh[64 + j];
  float ig = gin[128 + j] + bih[128 + j], hg = ghn[128 + j] + bhh[128 + j];
  float r = 1.f / (1.f + expf(-(ir + hr)));
  float z = 1.f / (1.f + expf(-(iz + hz)));
  float ng = tanhf(ig + r * hg);
  hnext[idx] = (1.f - z) * ng + z * hprev[idx];
}

// ---------------- classifier final: out = u @ Wc2 + bc2 (u already BN+ReLU'd) ----------------
__global__ __launch_bounds__(256) void final_k(const float* __restrict__ u, const float* __restrict__ Wc2,
                                               const float* __restrict__ bc2, float* __restrict__ out, int N) {
  __shared__ float Wl[128 * 4];
  for (int i = threadIdx.x; i < 512; i += 256) Wl[i] = Wc2[i];
  __syncthreads();
  int idx = blockIdx.x * 256 + threadIdx.x;
  if (idx >= N * 4) return;
  int n = idx >> 2, c = idx & 3;
  const float* ur = u + (size_t)n * 128;
  float acc = bc2[c];
#pragma unroll 8
  for (int k = 0; k < 128; ++k) acc += ur[k] * Wl[k * 4 + c];
  out[idx] = acc;
}

extern "C" void kernel_launch(void* const* d_in, const int* in_sizes, int n_in,
                              void* d_out, int out_size, void* d_ws, size_t ws_size,
                              hipStream_t stream) {
  const float* xs   = (const float*)d_in[0];
  const int*   esrc = (const int*)d_in[1];
  const int*   edst = (const int*)d_in[2];
  const float* ew   = (const float*)d_in[3];
  const float* W1   = (const float*)d_in[4];
  const float* g1   = (const float*)d_in[6];
  const float* be1  = (const float*)d_in[7];
  const float* W2   = (const float*)d_in[8];
  const float* g2   = (const float*)d_in[10];
  const float* be2  = (const float*)d_in[11];
  const float* gW   = (const float*)d_in[12];
  const float* gg   = (const float*)d_in[14];
  const float* gbe  = (const float*)d_in[15];
  const float* Wp   = (const float*)d_in[16];
  const float* gp   = (const float*)d_in[18];
  const float* bep  = (const float*)d_in[19];
  const float* Wih  = (const float*)d_in[20];
  const float* Whh  = (const float*)d_in[21];
  const float* bih  = (const float*)d_in[22];
  const float* bhh  = (const float*)d_in[23];
  const float* Wc1  = (const float*)d_in[24];
  const float* gc   = (const float*)d_in[26];
  const float* bec  = (const float*)d_in[27];
  const float* Wc2  = (const float*)d_in[28];
  const float* bc2  = (const float*)d_in[29];
  float* out = (float*)d_out;

  const int T = 8;
  const int N = in_sizes[0] / (T * 32);
  const int E = in_sizes[1] / T;

  // ---- workspace layout ----
  size_t fH    = (size_t)T * N * 64;
  size_t fpool = (size_t)N * 512;           // max(encoder, gru) scratch
  size_t nfloat = fH + fpool + N + E + 512;
  size_t nint   = (size_t)4 * N + 257 + E;
  if (ws_size < (nfloat + nint) * 4) return;

  float* H     = (float*)d_ws;
  float* pool  = H + fH;
  float* deg   = pool + fpool;              // becomes dinv after rsqrt
  float* enorm = deg + N;
  float* stats = enorm + E;
  float* ssum  = stats;
  float* ssq   = stats + 256;
  int* cnt    = (int*)(stats + 512);
  int* incl   = cnt + N;
  int* rowptr = incl + N;
  int* bsum   = rowptr + (N + 1);
  int* cursor = bsum + 256;
  int* eidx   = cursor + N;

  // encoder scratch views
  float* y1 = pool;                   // [N,128]
  float* hb = pool + (size_t)N * 128; // [N,64]
  float* xw = hb + (size_t)N * 64;    // [N,64]
  float* ag = xw + (size_t)N * 64;    // [N,64]

  const int nb = CDIV(N, 256);        // scan blocks (196 for N=50000, must be <=256)
  const int SG = 1200;                // stats grid

  // ================= encoder over T timesteps =================
  for (int t = 0; t < T; ++t) {
    const float* xt = xs + (size_t)t * N * 32;
    const int*   st = esrc + (size_t)t * E;
    const int*   dt = edst + (size_t)t * E;
    const float* wt = ew + (size_t)t * E;

    // MLP1: [N,32]@[32,128] -> BN+ReLU (bias cancels in BN)
    gemm_k<32, 128, 8, false><<<CDIV(N, 16), 256, 0, stream>>>(xt, W1, y1, N);
    hipMemsetAsync(stats, 0, 512 * sizeof(float), stream);
    stats_k<128><<<SG, 256, 0, stream>>>(y1, ssum, ssq, N);
    bnrelu_k<<<CDIV(N * 128, 256), 256, 0, stream>>>(y1, y1, ssum, ssq, g1, be1, N, 128, 0);

    // MLP2: [N,128]@[128,64] -> BN+ReLU
    gemm_k<128, 64, 8, false><<<CDIV(N, 32), 256, 0, stream>>>(y1, W2, hb, N);
    hipMemsetAsync(stats, 0, 512 * sizeof(float), stream);
    stats_k<64><<<SG, 256, 0, stream>>>(hb, ssum, ssq, N);
    bnrelu_k<<<CDIV(N * 64, 256), 256, 0, stream>>>(hb, hb, ssum, ssq, g2, be2, N, 64, 0);

    // graph prep (shared by the 3 GCN layers)
    fill_k<<<CDIV(N, 256), 256, 0, stream>>>(deg, 1.0f, N);
    deg_k<<<CDIV(E, 256), 256, 0, stream>>>(dt, wt, deg, E);
    rsqrt_k<<<CDIV(N, 256), 256, 0, stream>>>(deg, N);
    hipMemsetAsync(cnt, 0, (size_t)N * 4, stream);
    hist_k<<<CDIV(E, 256), 256, 0, stream>>>(dt, cnt, E);
    scan_block<<<nb, 256, 0, stream>>>(cnt, N, incl, bsum);
    scan_block<<<1, 256, 0, stream>>>(bsum, nb, bsum, nullptr);
    scan3_k<<<nb, 256, 0, stream>>>(incl, cnt, bsum, rowptr, N, E);
    copy_k<<<CDIV(N, 256), 256, 0, stream>>>(rowptr, cursor, N);
    scatter_k<<<CDIV(E, 256), 256, 0, stream>>>(st, dt, wt, deg, cursor, eidx, enorm, E);

    // 3 GCN blocks with residual
    for (int l = 0; l < 3; ++l) {
      gemm_k<64, 64, 8, false><<<CDIV(N, 32), 256, 0, stream>>>(hb, gW + (size_t)l * 64 * 64, xw, N);
      agg_k<<<CDIV(N, 4), 256, 0, stream>>>(xw, deg, rowptr, eidx, enorm, ag, N);
      hipMemsetAsync(stats, 0, 512 * sizeof(float), stream);
      stats_k<64><<<SG, 256, 0, stream>>>(ag, ssum, ssq, N);
      bnrelu_k<<<CDIV(N * 64, 256), 256, 0, stream>>>(ag, hb, ssum, ssq, gg + l * 64, gbe + l * 64, N, 64, 1);
    }

    // post MLP -> H[t]
    gemm_k<64, 64, 8, false><<<CDIV(N, 32), 256, 0, stream>>>(hb, Wp, xw, N);
    hipMemsetAsync(stats, 0, 512 * sizeof(float), stream);
    stats_k<64><<<SG, 256, 0, stream>>>(xw, ssum, ssq, N);
    bnrelu_k<<<CDIV(N * 64, 256), 256, 0, stream>>>(xw, H + (size_t)t * N * 64, ssum, ssq, gp, bep, N, 64, 0);
  }

  // ================= GRU over T steps =================
  float* gi = pool;
  float* gh = gi + (size_t)N * 192;
  float* hA = gh + (size_t)N * 192;
  float* hB = hA + (size_t)N * 64;
  hipMemsetAsync(hA, 0, (size_t)N * 64 * 4, stream);
  float* hprev = hA; float* hnext = hB;
  for (int t = 0; t < T; ++t) {
    gemm_k<64, 192, 6, true><<<CDIV(N, 8), 256, 0, stream>>>(H + (size_t)t * N * 64, Wih, gi, N);
    gemm_k<64, 192, 6, true><<<CDIV(N, 8), 256, 0, stream>>>(hprev, Whh, gh, N);
    gru_gate_k<<<CDIV(N * 64, 256), 256, 0, stream>>>(gi, gh, bih, bhh, hprev, hnext, N);
    float* tmp = hprev; hprev = hnext; hnext = tmp;
  }
  // after 8 steps, hprev == hA holds h_T (pool + N*384), safely past u below

  // ================= classifier =================
  float* u = pool;  // [N,128]
  gemm_k<64, 128, 8, false><<<CDIV(N, 16), 256, 0, stream>>>(hprev, Wc1, u, N);
  hipMemsetAsync(stats, 0, 512 * sizeof(float), stream);
  stats_k<128><<<SG, 256, 0, stream>>>(u, ssum, ssq, N);
  bnrelu_k<<<CDIV(N * 128, 256), 256, 0, stream>>>(u, u, ssum, ssq, gc, bec, N, 128, 0);
  final_k<<<CDIV(N * 4, 256), 256, 0, stream>>>(u, Wc2, bc2, out, N);
}

// Round 2
// 5967.096 us; speedup vs baseline: 1.5567x; 1.5567x over previous
//
#include <hip/hip_runtime.h>
#include <hip/hip_bf16.h>
#include <cstddef>

#define CDIV(a,b) (((a)+(b)-1)/(b))

static constexpr float BN_EPS = 1e-5f;

__device__ inline ushort f2bf(float x) {
  unsigned u = __float_as_uint(x);
  unsigned r = (u + 0x7fffu + ((u >> 16) & 1u)) >> 16;
  return (ushort)r;
}
__device__ inline float bf2f(ushort h) {
  return __uint_as_float(((unsigned)h) << 16);
}

// =====================================================================
// Register-tiled fp32 GEMM: C[N,M] = A[N,K] @ Weff[K,M]
// Weff[k][m] = TRANSW ? W[m*K+k] : W[k*M+m]
// TR=8 rows x TM=8 cols per thread. K tiled by KT=32.
// BNA: apply BN(stats aStat, gamma aG, beta aB over A's K columns)+ReLU to A on load.
// FSTAT: accumulate per-column sum/sumsq of raw output into oStat[0..M)/[128..128+M).
// OBF16: write bf16 output to Cb instead of float C.
// Stats slot layout: sum[c] at slot[c], sumsq[c] at slot[128+c].
// =====================================================================
template<int K, int M, int ROWS, bool TRANSW, bool BNA, bool FSTAT, bool OBF16>
__global__ __launch_bounds__((M / 8) * (ROWS / 8))
void gemm_rt(const float* __restrict__ A, const float* __restrict__ W,
             float* __restrict__ C, ushort* __restrict__ Cb,
             const float* __restrict__ aStat, const float* __restrict__ aG,
             const float* __restrict__ aB, float* __restrict__ oStat, int N) {
  constexpr int TM = 8, TR = 8, KT = 32;
  constexpr int CGS = M / TM;
  constexpr int THREADS = CGS * (ROWS / TR);
  constexpr int WROW = K * TM + 4;
  constexpr int APAD = ROWS + 4;
  __shared__ float Ws[CGS * WROW];
  __shared__ float As[KT * APAD];
  __shared__ float bnSc[BNA ? K : 1], bnSh[BNA ? K : 1];
  __shared__ float redS[FSTAT ? M : 1], redQ[FSTAT ? M : 1];

  const int tid = threadIdx.x;
  // ---- stage W (swizzled per column-group) ----
  for (int i = tid; i < K * M; i += THREADS) {
    int k = i / M, m = i - k * M;
    float wv = TRANSW ? W[m * K + k] : W[i];
    int cg = m / TM, j = m - cg * TM;
    Ws[cg * WROW + k * TM + j] = wv;
  }
  if (BNA) {
    float invN = 1.f / (float)N;
    for (int i = tid; i < K; i += THREADS) {
      float mn = aStat[i] * invN;
      float vr = fmaxf(aStat[128 + i] * invN - mn * mn, 0.f);
      float sc = aG[i] * rsqrtf(vr + BN_EPS);
      bnSc[i] = sc;
      bnSh[i] = aB[i] - mn * sc;
    }
  }
  if (FSTAT) {
    if (tid < M) { redS[tid] = 0.f; redQ[tid] = 0.f; }
  }

  const int cg = tid % CGS, rg = tid / CGS;
  const int r0 = rg * TR;
  const int row0 = blockIdx.x * ROWS;
  float acc[TR][TM];
#pragma unroll
  for (int i = 0; i < TR; ++i)
#pragma unroll
    for (int j = 0; j < TM; ++j) acc[i][j] = 0.f;

  constexpr int F4 = KT / 4;
  for (int kt = 0; kt < K; kt += KT) {
    __syncthreads();  // protects As reuse; first iter: pairs with W/bn staging
    for (int i = tid; i < ROWS * F4; i += THREADS) {
      int r = i / F4, f = i - r * F4;
      int grow = row0 + r;
      float4 v = make_float4(0.f, 0.f, 0.f, 0.f);
      if (grow < N) v = *(const float4*)&A[(size_t)grow * K + kt + f * 4];
      float vv[4];
      *(float4*)vv = v;
      if (BNA) {
#pragma unroll
        for (int c = 0; c < 4; ++c)
          vv[c] = fmaxf(fmaf(vv[c], bnSc[kt + f * 4 + c], bnSh[kt + f * 4 + c]), 0.f);
      }
#pragma unroll
      for (int c = 0; c < 4; ++c) As[(f * 4 + c) * APAD + r] = vv[c];
    }
    __syncthreads();
    const float* ap = As + r0;
    const float* wp = Ws + cg * WROW + kt * TM;
#pragma unroll 4
    for (int k = 0; k < KT; ++k) {
      float a[8], w[8];
      *(float4*)&a[0] = *(const float4*)(ap + k * APAD);
      *(float4*)&a[4] = *(const float4*)(ap + k * APAD + 4);
      *(float4*)&w[0] = *(const float4*)(wp + k * TM);
      *(float4*)&w[4] = *(const float4*)(wp + k * TM + 4);
#pragma unroll
      for (int i = 0; i < TR; ++i)
#pragma unroll
        for (int j = 0; j < TM; ++j) acc[i][j] = fmaf(a[i], w[j], acc[i][j]);
    }
  }

  const int colBase = cg * TM;
#pragma unroll
  for (int i = 0; i < TR; ++i) {
    int grow = row0 + r0 + i;
    if (grow < N) {
      if (OBF16) {
        ushort h8[8];
#pragma unroll
        for (int j = 0; j < TM; ++j) h8[j] = f2bf(acc[i][j]);
        *(float4*)&Cb[(size_t)grow * M + colBase] = *(float4*)h8;
      } else {
        *(float4*)&C[(size_t)grow * M + colBase] = *(const float4*)&acc[i][0];
        *(float4*)&C[(size_t)grow * M + colBase + 4] = *(const float4*)&acc[i][4];
      }
    }
  }
  if (FSTAT) {
    float s[8], q[8];
#pragma unroll
    for (int j = 0; j < TM; ++j) { s[j] = 0.f; q[j] = 0.f; }
#pragma unroll
    for (int i = 0; i < TR; ++i) {
      if (row0 + r0 + i < N) {
#pragma unroll
        for (int j = 0; j < TM; ++j) {
          s[j] += acc[i][j];
          q[j] += acc[i][j] * acc[i][j];
        }
      }
    }
    __syncthreads();  // redS/redQ zeroed before use (done at top, but ensure visibility)
#pragma unroll
    for (int j = 0; j < TM; ++j) {
      atomicAdd(&redS[colBase + j], s[j]);
      atomicAdd(&redQ[colBase + j], q[j]);
    }
    __syncthreads();
    if (tid < M) {
      atomicAdd(&oStat[tid], redS[tid]);
      atomicAdd(&oStat[128 + tid], redQ[tid]);
    }
  }
}

// ---------------- efficient column stats over [N,M] ----------------
template<int M>
__global__ __launch_bounds__(256) void stats2_k(const float* __restrict__ X,
                                                float* __restrict__ oStat, int N) {
  __shared__ float rs[M], rq[M];
  if (threadIdx.x < M) { rs[threadIdx.x] = 0.f; rq[threadIdx.x] = 0.f; }
  __syncthreads();
  constexpr int RPB = 256 / M;
  int col = threadIdx.x % M;
  int r = blockIdx.x * RPB + threadIdx.x / M;
  float s = 0.f, q = 0.f;
  for (; r < N; r += gridDim.x * RPB) {
    float v = X[(size_t)r * M + col];
    s += v;
    q += v * v;
  }
  atomicAdd(&rs[col], s);
  atomicAdd(&rq[col], q);
  __syncthreads();
  if (threadIdx.x < M) {
    atomicAdd(&oStat[threadIdx.x], rs[threadIdx.x]);
    atomicAdd(&oStat[128 + threadIdx.x], rq[threadIdx.x]);
  }
}

// ---------------- BN(train stats)+ReLU, float4, optional residual add ----------------
__global__ __launch_bounds__(256) void bnrelu_k(const float* __restrict__ X, float* __restrict__ Y,
                                                const float* __restrict__ st,
                                                const float* __restrict__ g, const float* __restrict__ be,
                                                int N, int M, int residual) {
  size_t i4 = (size_t)blockIdx.x * 256 + threadIdx.x;
  size_t total = (size_t)N * M / 4;
  if (i4 >= total) return;
  int c0 = (int)((i4 * 4) % M);
  float invN = 1.f / (float)N;
  float4 x = ((const float4*)X)[i4];
  float xv[4];
  *(float4*)xv = x;
  float yv[4];
#pragma unroll
  for (int j = 0; j < 4; ++j) {
    int c = c0 + j;
    float mn = st[c] * invN;
    float vr = fmaxf(st[128 + c] * invN - mn * mn, 0.f);
    float sc = g[c] * rsqrtf(vr + BN_EPS);
    float v = (xv[j] - mn) * sc + be[c];
    yv[j] = fmaxf(v, 0.f);
  }
  if (residual) {
    float4 o = ((const float4*)Y)[i4];
    yv[0] += o.x; yv[1] += o.y; yv[2] += o.z; yv[3] += o.w;
  }
  ((float4*)Y)[i4] = *(float4*)yv;
}

// ---------------- graph prep ----------------
__global__ void init_k(float* __restrict__ deg, int* __restrict__ cnt, int n) {
  int i = blockIdx.x * 256 + threadIdx.x;
  if (i < n) { deg[i] = 1.0f; cnt[i] = 0; }
}
__global__ void edge_pass_k(const int* __restrict__ dst, const float* __restrict__ w,
                            float* __restrict__ deg, int* __restrict__ cnt, int E) {
  int e = blockIdx.x * 256 + threadIdx.x;
  if (e < E) {
    int d = dst[e];
    atomicAdd(&deg[d], w[e]);
    atomicAdd(&cnt[d], 1);
  }
}
__global__ void rsqrt_k(float* p, int n) {
  int i = blockIdx.x * 256 + threadIdx.x;
  if (i < n) p[i] = rsqrtf(p[i]);
}
__global__ __launch_bounds__(256) void scan_block(const int* __restrict__ in, int n,
                                                  int* __restrict__ incl, int* __restrict__ bsum) {
  int i = blockIdx.x * 256 + threadIdx.x;
  int v = (i < n) ? in[i] : 0;
  int lane = threadIdx.x & 63;
  int sidx = threadIdx.x >> 6;
  int sv = v;
  for (int off = 1; off < 64; off <<= 1) {
    int t = __shfl_up(sv, off, 64);
    if (lane >= off) sv += t;
  }
  __shared__ int wsum[4];
  if (lane == 63) wsum[sidx] = sv;
  __syncthreads();
  int add = 0;
  for (int w = 0; w < sidx; ++w) add += wsum[w];
  sv += add;
  if (i < n) incl[i] = sv;
  if (threadIdx.x == 255 && bsum) bsum[blockIdx.x] = sv;
}
__global__ void scan3_k(const int* __restrict__ incl, const int* __restrict__ cnt,
                        const int* __restrict__ bincl, int* __restrict__ rowptr,
                        int* __restrict__ cursor, int n, int E) {
  int i = blockIdx.x * 256 + threadIdx.x;
  if (i < n) {
    int v = incl[i] - cnt[i] + (blockIdx.x ? bincl[blockIdx.x - 1] : 0);
    rowptr[i] = v;
    cursor[i] = v;
  }
  if (i == 0) rowptr[n] = E;
}
__global__ void scatter_k(const int* __restrict__ src, const int* __restrict__ dst,
                          const float* __restrict__ w, const float* __restrict__ dinv,
                          int* __restrict__ cursor, int* __restrict__ eidx,
                          float* __restrict__ enorm, int E) {
  int e = blockIdx.x * 256 + threadIdx.x;
  if (e >= E) return;
  int d = dst[e], s2 = src[e];
  int pos = atomicAdd(&cursor[d], 1);
  eidx[pos] = s2;
  enorm[pos] = dinv[s2] * w[e] * dinv[d];
}

// ---------------- GCN aggregation over bf16 features ----------------
__global__ __launch_bounds__(256) void agg_k(const ushort* __restrict__ xw, const float* __restrict__ dinv,
                                             const int* __restrict__ rowptr, const int* __restrict__ eidx,
                                             const float* __restrict__ enorm, float* __restrict__ agg, int N) {
  int wv = (blockIdx.x * 256 + threadIdx.x) >> 6;
  int f = threadIdx.x & 63;
  if (wv >= N) return;
  float di = dinv[wv];
  float acc = bf2f(xw[(size_t)wv * 64 + f]) * di * di;  // self loop
  int b = rowptr[wv], e = rowptr[wv + 1];
  for (int j = b; j < e; ++j) {
    acc += bf2f(xw[(size_t)eidx[j] * 64 + f]) * enorm[j];
  }
  agg[(size_t)wv * 64 + f] = acc;
}

// ---------------- GRU gate fusion ----------------
__global__ __launch_bounds__(256) void gru_gate_k(const float* __restrict__ gi, const float* __restrict__ gh,
                                                  const float* __restrict__ bih, const float* __restrict__ bhh,
                                                  const float* __restrict__ hprev, float* __restrict__ hnext, int N) {
  int idx = blockIdx.x * 256 + threadIdx.x;
  if (idx >= N * 64) return;
  int n = idx >> 6, j = idx & 63;
  const float* gin = gi + (size_t)n * 192;
  const float* ghn = gh + (size_t)n * 192;
  float ir = gin[j] + bih[j], hr = ghn[j] + bhh[j];
  float iz = gin[64 + j] + bih[64 + j], hz = ghn[64 + j] + bhh[64 + j];
  float ig = gin[128 + j] + bih[128 + j], hg = ghn[128 + j] + bhh[128 + j];
  float r = 1.f / (1.f + expf(-(ir + hr)));
  float z = 1.f / (1.f + expf(-(iz + hz)));
  float ng = tanhf(ig + r * hg);
  hnext[idx] = (1.f - z) * ng + z * hprev[idx];
}

// ---------------- classifier final: BN+ReLU(u) @ Wc2 + bc2 ----------------
__global__ __launch_bounds__(256) void final_k(const float* __restrict__ u, const float* __restrict__ st,
                                               const float* __restrict__ g, const float* __restrict__ be,
                                               const float* __restrict__ Wc2, const float* __restrict__ bc2,
                                               float* __restrict__ out, int N) {
  __shared__ float Wl[512], sc[128], sh[128];
  for (int i = threadIdx.x; i < 512; i += 256) Wl[i] = Wc2[i];
  if (threadIdx.x < 128) {
    int c = threadIdx.x;
    float invN = 1.f / (float)N;
    float mn = st[c] * invN;
    float vr = fmaxf(st[128 + c] * invN - mn * mn, 0.f);
    float s = g[c] * rsqrtf(vr + BN_EPS);
    sc[c] = s;
    sh[c] = be[c] - mn * s;
  }
  __syncthreads();
  int idx = blockIdx.x * 256 + threadIdx.x;
  if (idx >= N * 4) return;
  int n = idx >> 2, c = idx & 3;
  const float* ur = u + (size_t)n * 128;
  float acc = bc2[c];
#pragma unroll 8
  for (int k = 0; k < 128; ++k) {
    float v = fmaxf(fmaf(ur[k], sc[k], sh[k]), 0.f);
    acc = fmaf(v, Wl[k * 4 + c], acc);
  }
  out[idx] = acc;
}

extern "C" void kernel_launch(void* const* d_in, const int* in_sizes, int n_in,
                              void* d_out, int out_size, void* d_ws, size_t ws_size,
                              hipStream_t stream) {
  const float* xs   = (const float*)d_in[0];
  const int*   esrc = (const int*)d_in[1];
  const int*   edst = (const int*)d_in[2];
  const float* ew   = (const float*)d_in[3];
  const float* W1   = (const float*)d_in[4];
  const float* g1   = (const float*)d_in[6];
  const float* be1  = (const float*)d_in[7];
  const float* W2   = (const float*)d_in[8];
  const float* g2   = (const float*)d_in[10];
  const float* be2  = (const float*)d_in[11];
  const float* gW   = (const float*)d_in[12];
  const float* gg   = (const float*)d_in[14];
  const float* gbe  = (const float*)d_in[15];
  const float* Wp   = (const float*)d_in[16];
  const float* gp   = (const float*)d_in[18];
  const float* bep  = (const float*)d_in[19];
  const float* Wih  = (const float*)d_in[20];
  const float* Whh  = (const float*)d_in[21];
  const float* bih  = (const float*)d_in[22];
  const float* bhh  = (const float*)d_in[23];
  const float* Wc1  = (const float*)d_in[24];
  const float* gc   = (const float*)d_in[26];
  const float* bec  = (const float*)d_in[27];
  const float* Wc2  = (const float*)d_in[28];
  const float* bc2  = (const float*)d_in[29];
  float* out = (float*)d_out;

  const int T = 8;
  const int N = in_sizes[0] / (T * 32);
  const int E = in_sizes[1] / T;

  // ---- workspace layout ----
  size_t fH    = (size_t)T * N * 64;
  size_t fpool = (size_t)N * 512;
  size_t nStat = 49 * 256;
  size_t nfloat = fH + fpool + N + E + nStat;
  size_t nint = (size_t)4 * N + 257 + E;
  if (ws_size < (nfloat + nint) * 4) return;

  float* H     = (float*)d_ws;
  float* pool  = H + fH;
  float* deg   = pool + fpool;    // becomes dinv after rsqrt
  float* enorm = deg + N;
  float* statsA = enorm + E;      // 49 slots of 256 floats
  int* cnt    = (int*)(statsA + nStat);
  int* incl   = cnt + N;
  int* rowptr = incl + N;
  int* bsum   = rowptr + (N + 1);
  int* cursor = bsum + 256;
  int* eidx   = cursor + N;

  // encoder scratch views
  float* y1  = pool;                    // [N,128]
  float* hb  = pool + (size_t)N * 128;  // [N,64]
  float* xwf = hb + (size_t)N * 64;     // [N,64] float (post-mlp); also bf16 xw
  ushort* xwb = (ushort*)xwf;           // [N,64] bf16
  float* ag  = xwf + (size_t)N * 64;    // [N,64]

  const int nb = CDIV(N, 256);

#define SLOT(t, j) (statsA + ((size_t)(t) * 6 + (j)) * 256)

  // zero all stats slots once per launch (part of the captured graph)
  hipMemsetAsync(statsA, 0, nStat * sizeof(float), stream);

  // ================= encoder over T timesteps =================
  for (int t = 0; t < T; ++t) {
    const float* xt = xs + (size_t)t * N * 32;
    const int*   st = esrc + (size_t)t * E;
    const int*   dt = edst + (size_t)t * E;
    const float* wt = ew + (size_t)t * E;

    // MLP1: raw y1 + stats(y1)
    gemm_rt<32, 128, 64, false, false, true, false><<<CDIV(N, 64), 128, 0, stream>>>(
        xt, W1, y1, nullptr, nullptr, nullptr, nullptr, SLOT(t, 0), N);
    // MLP2: BN+ReLU(y1) folded into A-load, raw hb + stats(hb)
    gemm_rt<128, 64, 128, false, true, true, false><<<CDIV(N, 128), 128, 0, stream>>>(
        y1, W2, hb, nullptr, SLOT(t, 0), g1, be1, SLOT(t, 1), N);
    bnrelu_k<<<CDIV(N * 64 / 4, 256), 256, 0, stream>>>(hb, hb, SLOT(t, 1), g2, be2, N, 64, 0);

    // graph prep (shared by the 3 GCN layers)
    init_k<<<CDIV(N, 256), 256, 0, stream>>>(deg, cnt, N);
    edge_pass_k<<<CDIV(E, 256), 256, 0, stream>>>(dt, wt, deg, cnt, E);
    rsqrt_k<<<CDIV(N, 256), 256, 0, stream>>>(deg, N);
    scan_block<<<nb, 256, 0, stream>>>(cnt, N, incl, bsum);
    scan_block<<<1, 256, 0, stream>>>(bsum, nb, bsum, nullptr);
    scan3_k<<<nb, 256, 0, stream>>>(incl, cnt, bsum, rowptr, cursor, N, E);
    scatter_k<<<CDIV(E, 256), 256, 0, stream>>>(st, dt, wt, deg, cursor, eidx, enorm, E);

    // 3 GCN blocks with residual
    for (int l = 0; l < 3; ++l) {
      gemm_rt<64, 64, 128, false, false, false, true><<<CDIV(N, 128), 128, 0, stream>>>(
          hb, gW + (size_t)l * 64 * 64, nullptr, xwb, nullptr, nullptr, nullptr, nullptr, N);
      agg_k<<<CDIV(N, 4), 256, 0, stream>>>(xwb, deg, rowptr, eidx, enorm, ag, N);
      stats2_k<64><<<256, 256, 0, stream>>>(ag, SLOT(t, 2 + l), N);
      bnrelu_k<<<CDIV(N * 64 / 4, 256), 256, 0, stream>>>(ag, hb, SLOT(t, 2 + l), gg + l * 64, gbe + l * 64, N, 64, 1);
    }

    // post MLP -> H[t]
    gemm_rt<64, 64, 128, false, false, true, false><<<CDIV(N, 128), 128, 0, stream>>>(
        hb, Wp, xwf, nullptr, nullptr, nullptr, nullptr, SLOT(t, 5), N);
    bnrelu_k<<<CDIV(N * 64 / 4, 256), 256, 0, stream>>>(xwf, H + (size_t)t * N * 64, SLOT(t, 5), gp, bep, N, 64, 0);
  }

  // ================= GRU over T steps =================
  float* gi = pool;
  float* gh = gi + (size_t)N * 192;
  float* hA = gh + (size_t)N * 192;
  float* hB = hA + (size_t)N * 64;
  hipMemsetAsync(hA, 0, (size_t)N * 64 * sizeof(float), stream);
  float* hprev = hA;
  float* hnext = hB;
  for (int t = 0; t < T; ++t) {
    gemm_rt<64, 192, 64, true, false, false, false><<<CDIV(N, 64), 192, 0, stream>>>(
        H + (size_t)t * N * 64, Wih, gi, nullptr, nullptr, nullptr, nullptr, nullptr, N);
    gemm_rt<64, 192, 64, true, false, false, false><<<CDIV(N, 64), 192, 0, stream>>>(
        hprev, Whh, gh, nullptr, nullptr, nullptr, nullptr, nullptr, N);
    gru_gate_k<<<CDIV(N * 64, 256), 256, 0, stream>>>(gi, gh, bih, bhh, hprev, hnext, N);
    float* tmp = hprev; hprev = hnext; hnext = tmp;
  }
  // after 8 steps hprev == hA (pool + N*384)

  // ================= classifier =================
  float* u = pool;  // [N,128] raw
  gemm_rt<64, 128, 64, false, false, true, false><<<CDIV(N, 64), 128, 0, stream>>>(
      hprev, Wc1, u, nullptr, nullptr, nullptr, nullptr, statsA + 48 * 256, N);
  final_k<<<CDIV(N * 4, 256), 256, 0, stream>>>(u, statsA + 48 * 256, gc, bec, Wc2, bc2, out, N);
}

// Round 5
// 5044.538 us; speedup vs baseline: 1.8414x; 1.1829x over previous
//
#include <hip/hip_runtime.h>
#include <hip/hip_bf16.h>
#include <cstddef>

#define CDIV(a,b) (((a)+(b)-1)/(b))

static constexpr float BN_EPS = 1e-5f;

typedef __attribute__((ext_vector_type(8))) short short8v;   // 8 bf16 (4 VGPRs)
typedef __attribute__((ext_vector_type(4))) float f32x4;

__device__ inline ushort f2bf(float x) {
  unsigned u = __float_as_uint(x);
  unsigned r = (u + 0x7fffu + ((u >> 16) & 1u)) >> 16;
  return (ushort)r;
}
__device__ inline float bf2f(ushort h) {
  return __uint_as_float(((unsigned)h) << 16);
}

// =====================================================================
// bf16 MFMA GEMM: C[N,M] = A[N,K] @ Weff[K,M]   (fp32 accumulate)
// Weff[k][m] = TRANSW ? W[m*K+k] : W[k*M+m]
// BM=128 rows/block, 256 threads (4 waves), wave -> 32 rows (2 rowtiles).
// BNA: fold BN(aStat,aG,aB over A's K cols)+ReLU into A staging.
//   NOTE: bnSc/bnSh are produced by a subset of threads and consumed by ALL
//   threads in A-staging -> REQUIRES a __syncthreads() in between (the round-3/4
//   failure was exactly this missing barrier).
// FSTAT: per-column sum/sumsq of fp32 accumulators -> oStat[c], oStat[128+c].
// INF32: A is fp32 (else bf16). OUTF32: write fp32 (else bf16).
// =====================================================================
template<int K, int M, bool TRANSW, bool BNA, bool FSTAT, bool INF32, bool OUTF32>
__global__ __launch_bounds__(256)
void gemm_mfma(const void* __restrict__ Ain, const float* __restrict__ W,
               void* __restrict__ Cout,
               const float* __restrict__ aStat, const float* __restrict__ aG,
               const float* __restrict__ aB, float* __restrict__ oStat, int N) {
  constexpr int BM = 128;
  constexpr int NKC = K / 32;
  constexpr int NMT = M / 16;
  __shared__ __align__(16) ushort As[BM * K];
  __shared__ __align__(16) ushort Wf[M * K];
  __shared__ float bnSc[BNA ? K : 1];
  __shared__ float bnSh[BNA ? K : 1];
  __shared__ float redS[FSTAT ? M : 1];
  __shared__ float redQ[FSTAT ? M : 1];
  const int tid = threadIdx.x;
  const int row0 = blockIdx.x * BM;

  // ---- W -> fragment-ordered bf16 LDS (lane=(kr/8)*16+m%16, elem=kr%8) ----
  for (int i = tid; i < K * M; i += 256) {
    int k, m;
    if (TRANSW) { m = i / K; k = i - m * K; }
    else        { k = i / M; m = i - k * M; }
    float wv = W[i];
    int mt = m >> 4, ml = m & 15, kc = k >> 5, kr = k & 31;
    int lane = ((kr >> 3) << 4) | ml;
    int j = kr & 7;
    Wf[(size_t)((mt * NKC + kc) * 64 + lane) * 8 + j] = f2bf(wv);
  }
  if (BNA) {
    float invN = 1.f / (float)N;
    for (int i = tid; i < K; i += 256) {
      float mn = aStat[i] * invN;
      float vr = fmaxf(aStat[128 + i] * invN - mn * mn, 0.f);
      float sc = aG[i] * rsqrtf(vr + BN_EPS);
      bnSc[i] = sc;
      bnSh[i] = aB[i] - mn * sc;
    }
    __syncthreads();  // *** THE FIX: bnSc/bnSh visible to all threads before A-staging ***
  }
  if (FSTAT) {
    if (tid < M) { redS[tid] = 0.f; redQ[tid] = 0.f; }
  }

  // ---- A -> XOR-swizzled bf16 LDS (optional BN+ReLU) ----
  {
    const float* Af = (const float*)Ain;
    const ushort* Ab = (const ushort*)Ain;
    for (int i = tid; i < BM * K / 4; i += 256) {
      int row = (i * 4) / K, k0 = (i * 4) % K;
      int grow = row0 + row;
      ushort h4[4] = {0, 0, 0, 0};
      if (!INF32 && !BNA) {
        if (grow < N) *(ushort4*)h4 = *(const ushort4*)&Ab[(size_t)grow * K + k0];
      } else {
        float vv[4] = {0.f, 0.f, 0.f, 0.f};
        if (grow < N) {
          if (INF32) {
            float4 v = *(const float4*)&Af[(size_t)grow * K + k0];
            *(float4*)vv = v;
          } else {
            ushort t4[4];
            *(ushort4*)t4 = *(const ushort4*)&Ab[(size_t)grow * K + k0];
#pragma unroll
            for (int c = 0; c < 4; ++c) vv[c] = bf2f(t4[c]);
          }
        }
        if (BNA) {
#pragma unroll
          for (int c = 0; c < 4; ++c)
            vv[c] = fmaxf(fmaf(vv[c], bnSc[k0 + c], bnSh[k0 + c]), 0.f);
        }
#pragma unroll
        for (int c = 0; c < 4; ++c) h4[c] = f2bf(vv[c]);
      }
      unsigned off = ((unsigned)(row * K + k0) * 2u) ^ (((unsigned)(row & 7)) << 4);
      *(ushort4*)((char*)As + off) = *(ushort4*)h4;
    }
  }
  __syncthreads();

  // ---- MFMA compute ----
  const int wvi = tid >> 6, lane = tid & 63;
  const int lrow = lane & 15, lkg = lane >> 4;

  short8v af[2][NKC];
#pragma unroll
  for (int rt = 0; rt < 2; ++rt)
#pragma unroll
    for (int kc = 0; kc < NKC; ++kc) {
      int row = wvi * 32 + rt * 16 + lrow;
      unsigned off = ((unsigned)(row * K + kc * 32 + lkg * 8) * 2u) ^ (((unsigned)(row & 7)) << 4);
      af[rt][kc] = *(const short8v*)((const char*)As + off);
    }

  f32x4 acc[2][NMT];
#pragma unroll
  for (int rt = 0; rt < 2; ++rt)
#pragma unroll
    for (int mt = 0; mt < NMT; ++mt) acc[rt][mt] = f32x4{0.f, 0.f, 0.f, 0.f};

#pragma unroll
  for (int mt = 0; mt < NMT; ++mt) {
    short8v bf[NKC];
#pragma unroll
    for (int kc = 0; kc < NKC; ++kc)
      bf[kc] = *(const short8v*)&Wf[(size_t)((mt * NKC + kc) * 64 + lane) * 8];
#pragma unroll
    for (int rt = 0; rt < 2; ++rt)
#pragma unroll
      for (int kc = 0; kc < NKC; ++kc)
        acc[rt][mt] = __builtin_amdgcn_mfma_f32_16x16x32_bf16(af[rt][kc], bf[kc], acc[rt][mt], 0, 0, 0);
  }

  // ---- C write, C/D layout: col=lane&15, row=(lane>>4)*4+i ----
#pragma unroll
  for (int rt = 0; rt < 2; ++rt)
#pragma unroll
    for (int mt = 0; mt < NMT; ++mt) {
#pragma unroll
      for (int i = 0; i < 4; ++i) {
        int grow = row0 + wvi * 32 + rt * 16 + lkg * 4 + i;
        if (grow < N) {
          if (OUTF32) ((float*)Cout)[(size_t)grow * M + mt * 16 + lrow] = acc[rt][mt][i];
          else        ((ushort*)Cout)[(size_t)grow * M + mt * 16 + lrow] = f2bf(acc[rt][mt][i]);
        }
      }
    }

  // ---- fused column stats from exact fp32 accumulators ----
  if (FSTAT) {
#pragma unroll
    for (int mt = 0; mt < NMT; ++mt) {
      float s = 0.f, q = 0.f;
#pragma unroll
      for (int rt = 0; rt < 2; ++rt)
#pragma unroll
        for (int i = 0; i < 4; ++i) {
          int grow = row0 + wvi * 32 + rt * 16 + lkg * 4 + i;
          if (grow < N) { float v = acc[rt][mt][i]; s += v; q += v * v; }
        }
      s += __shfl_xor(s, 16); s += __shfl_xor(s, 32);
      q += __shfl_xor(q, 16); q += __shfl_xor(q, 32);
      if (lkg == 0) {
        atomicAdd(&redS[mt * 16 + lrow], s);
        atomicAdd(&redQ[mt * 16 + lrow], q);
      }
    }
    __syncthreads();
    if (tid < M) {
      atomicAdd(&oStat[tid], redS[tid]);
      atomicAdd(&oStat[128 + tid], redQ[tid]);
    }
  }
}

// ---------------- BN+ReLU (fp32 raw in -> bf16 normalized out) ----------------
__global__ __launch_bounds__(256) void bnbf_k(const float* __restrict__ X, ushort* __restrict__ Y,
                                              const float* __restrict__ st,
                                              const float* __restrict__ g, const float* __restrict__ be,
                                              int N, int M) {
  int i4 = blockIdx.x * 256 + threadIdx.x;
  int total = N * M / 4;
  if (i4 >= total) return;
  int c0 = (i4 * 4) % M;
  float invN = 1.f / (float)N;
  float xv[4];
  *(float4*)xv = *(const float4*)&X[(size_t)i4 * 4];
  ushort yv[4];
#pragma unroll
  for (int j = 0; j < 4; ++j) {
    int c = c0 + j;
    float mn = st[c] * invN;
    float vr = fmaxf(st[128 + c] * invN - mn * mn, 0.f);
    float sc = g[c] * rsqrtf(vr + BN_EPS);
    float v = (xv[j] - mn) * sc + be[c];
    yv[j] = f2bf(fmaxf(v, 0.f));
  }
  *(ushort4*)&Y[(size_t)i4 * 4] = *(ushort4*)yv;
}

// ---------------- residual: Hc += relu(bn(Ag))  (Ag fp32, Hc bf16, M=64) ----------------
__global__ __launch_bounds__(256) void bnres_k(const float* __restrict__ Ag, ushort* __restrict__ Hc,
                                               const float* __restrict__ st,
                                               const float* __restrict__ g, const float* __restrict__ be,
                                               int N) {
  int i4 = blockIdx.x * 256 + threadIdx.x;
  int total = N * 16;  // N*64/4
  if (i4 >= total) return;
  int c0 = (i4 * 4) & 63;
  float invN = 1.f / (float)N;
  float av[4];
  *(float4*)av = *(const float4*)&Ag[(size_t)i4 * 4];
  ushort hv[4];
  *(ushort4*)hv = *(const ushort4*)&Hc[(size_t)i4 * 4];
  ushort ov[4];
#pragma unroll
  for (int j = 0; j < 4; ++j) {
    int c = c0 + j;
    float mn = st[c] * invN;
    float vr = fmaxf(st[128 + c] * invN - mn * mn, 0.f);
    float sc = g[c] * rsqrtf(vr + BN_EPS);
    float v = fmaxf((av[j] - mn) * sc + be[c], 0.f);
    ov[j] = f2bf(bf2f(hv[j]) + v);
  }
  *(ushort4*)&Hc[(size_t)i4 * 4] = *(ushort4*)ov;
}

// ---------------- batched graph prep ----------------
__global__ void hist_k(const int* __restrict__ dst, int* __restrict__ cnt, int* __restrict__ rank,
                       int TE, int N, int E) {
  int i = blockIdx.x * 256 + threadIdx.x;
  if (i >= TE) return;
  int t = i / E;
  rank[i] = atomicAdd(&cnt[t * N + dst[i]], 1);
}
__global__ __launch_bounds__(256) void scan1_k(const int* __restrict__ in, int* __restrict__ incl,
                                               int* __restrict__ bsum, int n) {
  int t = blockIdx.y;
  const int* inp = in + (size_t)t * n;
  int* ip = incl + (size_t)t * n;
  int i = blockIdx.x * 256 + threadIdx.x;
  int v = (i < n) ? inp[i] : 0;
  int lane = threadIdx.x & 63;
  int sidx = threadIdx.x >> 6;
  int sv = v;
  for (int off = 1; off < 64; off <<= 1) {
    int tt = __shfl_up(sv, off, 64);
    if (lane >= off) sv += tt;
  }
  __shared__ int wsum[4];
  if (lane == 63) wsum[sidx] = sv;
  __syncthreads();
  int add = 0;
  for (int w = 0; w < sidx; ++w) add += wsum[w];
  sv += add;
  if (i < n) ip[i] = sv;
  if (threadIdx.x == 255) bsum[t * 256 + blockIdx.x] = sv;
}
__global__ __launch_bounds__(256) void scan2_k(int* __restrict__ bsum, int nb) {
  int t = blockIdx.y;
  int* bp = bsum + t * 256;
  int i = threadIdx.x;
  int v = (i < nb) ? bp[i] : 0;
  int lane = threadIdx.x & 63;
  int sidx = threadIdx.x >> 6;
  int sv = v;
  for (int off = 1; off < 64; off <<= 1) {
    int tt = __shfl_up(sv, off, 64);
    if (lane >= off) sv += tt;
  }
  __shared__ int wsum[4];
  if (lane == 63) wsum[sidx] = sv;
  __syncthreads();
  int add = 0;
  for (int w = 0; w < sidx; ++w) add += wsum[w];
  sv += add;
  if (i < nb) bp[i] = sv;
}
__global__ void scan3_k(const int* __restrict__ incl, const int* __restrict__ cnt,
                        const int* __restrict__ bsum, int* __restrict__ rowptr, int n, int E) {
  int t = blockIdx.y;
  int i = blockIdx.x * 256 + threadIdx.x;
  int* rp = rowptr + (size_t)t * (n + 1);
  if (i < n) {
    int v = incl[(size_t)t * n + i] - cnt[(size_t)t * n + i] +
            (blockIdx.x ? bsum[t * 256 + blockIdx.x - 1] : 0);
    rp[i] = v;
  }
  if (i == 0) rp[n] = E;
}
__global__ void scat_k(const int* __restrict__ src, const int* __restrict__ dst,
                       const float* __restrict__ w, const int* __restrict__ rank,
                       const int* __restrict__ rowptr, int2* __restrict__ epk,
                       int TE, int N1, int E) {
  int i = blockIdx.x * 256 + threadIdx.x;
  if (i >= TE) return;
  int t = i / E;
  int slot = rowptr[(size_t)t * N1 + dst[i]] + rank[i];
  epk[(size_t)t * E + slot] = make_int2(src[i], __float_as_int(w[i]));
}
__global__ void deg_k(const int2* __restrict__ epk, const int* __restrict__ rowptr,
                      float* __restrict__ dinv, int TN, int N, int N1, int E) {
  int i = blockIdx.x * 256 + threadIdx.x;
  if (i >= TN) return;
  int t = i / N, n = i - t * N;
  const int* rp = rowptr + (size_t)t * N1;
  const int2* ep = epk + (size_t)t * E;
  float s = 1.f;  // self loop
  int b = rp[n], e = rp[n + 1];
  for (int j = b; j < e; ++j) s += __int_as_float(ep[j].y);
  dinv[i] = rsqrtf(s);
}
__global__ void norm_k(int2* __restrict__ epk, const int* __restrict__ rowptr,
                       const float* __restrict__ dinv, int TN, int N, int N1, int E) {
  int i = blockIdx.x * 256 + threadIdx.x;
  if (i >= TN) return;
  int t = i / N, n = i - t * N;
  const int* rp = rowptr + (size_t)t * N1;
  const float* dv = dinv + (size_t)t * N;
  int2* ep = epk + (size_t)t * E;
  float dn = dv[n];
  int b = rp[n], e = rp[n + 1];
  for (int j = b; j < e; ++j) {
    int2 ed = ep[j];
    ep[j].y = __float_as_int(dv[ed.x] * __int_as_float(ed.y) * dn);
  }
}

// ---------------- GCN aggregation (bf16 gather) + fused fp32 stats ----------------
__global__ __launch_bounds__(256) void agg_k(const ushort* __restrict__ xw, const float* __restrict__ dinv,
                                             const int* __restrict__ rowptr, const int2* __restrict__ epk,
                                             float* __restrict__ ag, float* __restrict__ oStat, int N) {
  __shared__ float redS[64], redQ[64];
  if (threadIdx.x < 64) { redS[threadIdx.x] = 0.f; redQ[threadIdx.x] = 0.f; }
  __syncthreads();
  int f = threadIdx.x & 63;
  int wvl = threadIdx.x >> 6;
  int stride = gridDim.x * 4;
  float s = 0.f, q = 0.f;
  for (int n = blockIdx.x * 4 + wvl; n < N; n += stride) {
    float di = dinv[n];
    float acc = bf2f(xw[(size_t)n * 64 + f]) * di * di;  // self loop
    int b = rowptr[n], e = rowptr[n + 1];
    for (int j = b; j < e; ++j) {
      int2 ed = epk[j];
      acc += bf2f(xw[(size_t)ed.x * 64 + f]) * __int_as_float(ed.y);
    }
    ag[(size_t)n * 64 + f] = acc;
    s += acc;
    q += acc * acc;
  }
  atomicAdd(&redS[f], s);
  atomicAdd(&redQ[f], q);
  __syncthreads();
  if (threadIdx.x < 64) {
    atomicAdd(&oStat[threadIdx.x], redS[threadIdx.x]);
    atomicAdd(&oStat[128 + threadIdx.x], redQ[threadIdx.x]);
  }
}

// ---------------- GRU gate fusion (bf16 gates/state) ----------------
__global__ __launch_bounds__(256) void gate_k(const ushort* __restrict__ gi, const ushort* __restrict__ gh,
                                              const float* __restrict__ bih, const float* __restrict__ bhh,
                                              const ushort* __restrict__ hprev, ushort* __restrict__ hnext,
                                              int N) {
  int idx = blockIdx.x * 256 + threadIdx.x;
  if (idx >= N * 64) return;
  int n = idx >> 6, j = idx & 63;
  const ushort* gin = gi + (size_t)n * 192;
  const ushort* ghn = gh + (size_t)n * 192;
  float ir = bf2f(gin[j]) + bih[j],             hr = bf2f(ghn[j]) + bhh[j];
  float iz = bf2f(gin[64 + j]) + bih[64 + j],   hz = bf2f(ghn[64 + j]) + bhh[64 + j];
  float ig = bf2f(gin[128 + j]) + bih[128 + j], hg = bf2f(ghn[128 + j]) + bhh[128 + j];
  float r = 1.f / (1.f + expf(-(ir + hr)));
  float z = 1.f / (1.f + expf(-(iz + hz)));
  float ng = tanhf(ig + r * hg);
  hnext[idx] = f2bf((1.f - z) * ng + z * bf2f(hprev[idx]));
}

// ---------------- classifier final: BN+ReLU(u fp32) @ Wc2 + bc2 ----------------
__global__ __launch_bounds__(256) void final_k(const float* __restrict__ u, const float* __restrict__ st,
                                               const float* __restrict__ g, const float* __restrict__ be,
                                               const float* __restrict__ Wc2, const float* __restrict__ bc2,
                                               float* __restrict__ out, int N) {
  __shared__ float Wl[512], sc[128], sh[128];
  for (int i = threadIdx.x; i < 512; i += 256) Wl[i] = Wc2[i];
  if (threadIdx.x < 128) {
    int c = threadIdx.x;
    float invN = 1.f / (float)N;
    float mn = st[c] * invN;
    float vr = fmaxf(st[128 + c] * invN - mn * mn, 0.f);
    float s = g[c] * rsqrtf(vr + BN_EPS);
    sc[c] = s;
    sh[c] = be[c] - mn * s;
  }
  __syncthreads();
  int idx = blockIdx.x * 256 + threadIdx.x;
  if (idx >= N * 4) return;
  int n = idx >> 2, c = idx & 3;
  const float* ur = u + (size_t)n * 128;
  float acc = bc2[c];
#pragma unroll 8
  for (int k = 0; k < 128; ++k) {
    float v = fmaxf(fmaf(ur[k], sc[k], sh[k]), 0.f);
    acc = fmaf(v, Wl[k * 4 + c], acc);
  }
  out[idx] = acc;
}

extern "C" void kernel_launch(void* const* d_in, const int* in_sizes, int n_in,
                              void* d_out, int out_size, void* d_ws, size_t ws_size,
                              hipStream_t stream) {
  const float* xs   = (const float*)d_in[0];
  const int*   esrc = (const int*)d_in[1];
  const int*   edst = (const int*)d_in[2];
  const float* ew   = (const float*)d_in[3];
  const float* W1   = (const float*)d_in[4];
  const float* g1   = (const float*)d_in[6];
  const float* be1  = (const float*)d_in[7];
  const float* W2   = (const float*)d_in[8];
  const float* g2   = (const float*)d_in[10];
  const float* be2  = (const float*)d_in[11];
  const float* gW   = (const float*)d_in[12];
  const float* gg   = (const float*)d_in[14];
  const float* gbe  = (const float*)d_in[15];
  const float* Wp   = (const float*)d_in[16];
  const float* gp   = (const float*)d_in[18];
  const float* bep  = (const float*)d_in[19];
  const float* Wih  = (const float*)d_in[20];
  const float* Whh  = (const float*)d_in[21];
  const float* bih  = (const float*)d_in[22];
  const float* bhh  = (const float*)d_in[23];
  const float* Wc1  = (const float*)d_in[24];
  const float* gc   = (const float*)d_in[26];
  const float* bec  = (const float*)d_in[27];
  const float* Wc2  = (const float*)d_in[28];
  const float* bc2  = (const float*)d_in[29];
  float* out = (float*)d_out;

  const int T = 8;
  const int N = in_sizes[0] / (T * 32);
  const int E = in_sizes[1] / T;
  const int TE = T * E, TN = T * N, N1 = N + 1;

  // ---- workspace layout (bytes) ----
  size_t off = 0;
  auto alloc = [&](size_t bytes) { size_t o = off; off += (bytes + 255) & ~(size_t)255; return o; };
  char* base = (char*)d_ws;
  size_t oH      = alloc((size_t)T * N * 64 * 2);   // H bf16
  size_t oEpk    = alloc((size_t)TE * 8);           // packed (src, w/norm)
  size_t oRp     = alloc((size_t)T * N1 * 4);       // rowptr
  size_t oDinv   = alloc((size_t)TN * 4);           // dinv
  size_t oStats  = alloc((size_t)49 * 256 * 4);     // stats slots
  size_t oBsum   = alloc((size_t)T * 256 * 4);      // scan block sums
  size_t oArena  = alloc((size_t)80 * 1024 * 1024); // phase-shared arena
  if (ws_size < off) return;

  ushort* H     = (ushort*)(base + oH);
  int2*   epk   = (int2*)(base + oEpk);
  int*    rowptr= (int*)(base + oRp);
  float*  dinv  = (float*)(base + oDinv);
  float*  statsA= (float*)(base + oStats);
  int*    bsum  = (int*)(base + oBsum);
  char*   arena = base + oArena;

  // prep-phase arena views
  int* cnt  = (int*)arena;                         // [T*N]
  int* incl = cnt + TN;                            // [T*N]
  int* rank = incl + TN;                           // [T*E]
  // encoder-phase arena views (raw pre-BN in fp32, normalized in bf16)
  float*  y1f  = (float*)arena;                    // [N,128] fp32 raw
  float*  hbf  = y1f + (size_t)N * 128;            // [N,64]  fp32 raw
  ushort* hcur = (ushort*)(hbf + (size_t)N * 64);  // [N,64]  bf16 normalized
  ushort* xwb  = hcur + (size_t)N * 64;            // [N,64]  bf16 (gather table)
  float*  ag   = (float*)(xwb + (size_t)N * 64);   // [N,64]  fp32 raw (agg / post-mlp)
  // gru/cls-phase arena views
  ushort* gi = (ushort*)arena;                     // [N,192] bf16
  ushort* gh = gi + (size_t)N * 192;               // [N,192] bf16
  ushort* hA = gh + (size_t)N * 192;               // [N,64]
  ushort* hB = hA + (size_t)N * 64;                // [N,64]
  float*  uf = (float*)arena;                      // [N,128] fp32 raw (gi/gh dead)

  const int nb = CDIV(N, 256);

#define SLOT(t, j) (statsA + ((size_t)(t) * 6 + (j)) * 256)

  hipMemsetAsync(statsA, 0, (size_t)49 * 256 * 4, stream);
  hipMemsetAsync(cnt, 0, (size_t)TN * 4, stream);

  // ================= batched graph prep (all T) =================
  hist_k<<<CDIV(TE, 256), 256, 0, stream>>>(edst, cnt, rank, TE, N, E);
  scan1_k<<<dim3(nb, T), 256, 0, stream>>>(cnt, incl, bsum, N);
  scan2_k<<<dim3(1, T), 256, 0, stream>>>(bsum, nb);
  scan3_k<<<dim3(nb, T), 256, 0, stream>>>(incl, cnt, bsum, rowptr, N, E);
  scat_k<<<CDIV(TE, 256), 256, 0, stream>>>(esrc, edst, ew, rank, rowptr, epk, TE, N1, E);
  deg_k<<<CDIV(TN, 256), 256, 0, stream>>>(epk, rowptr, dinv, TN, N, N1, E);
  norm_k<<<CDIV(TN, 256), 256, 0, stream>>>(epk, rowptr, dinv, TN, N, N1, E);

  const int gemmGrid = CDIV(N, 128);

  // ================= encoder over T timesteps =================
  for (int t = 0; t < T; ++t) {
    const float* xt = xs + (size_t)t * N * 32;
    const int* rpT = rowptr + (size_t)t * N1;
    const int2* epkT = epk + (size_t)t * E;
    const float* dinvT = dinv + (size_t)t * N;

    // MLP1: y1f(fp32 raw) = xt @ W1, stats -> SLOT(t,0)
    gemm_mfma<32, 128, false, false, true, true, true><<<gemmGrid, 256, 0, stream>>>(
        xt, W1, y1f, nullptr, nullptr, nullptr, SLOT(t, 0), N);
    // MLP2: hbf(fp32 raw) = BNReLU(y1f) @ W2, stats -> SLOT(t,1)
    gemm_mfma<128, 64, false, true, true, true, true><<<gemmGrid, 256, 0, stream>>>(
        y1f, W2, hbf, SLOT(t, 0), g1, be1, SLOT(t, 1), N);
    bnbf_k<<<CDIV(N * 16, 256), 256, 0, stream>>>(hbf, hcur, SLOT(t, 1), g2, be2, N, 64);

    // 3 GCN blocks with residual
    for (int l = 0; l < 3; ++l) {
      gemm_mfma<64, 64, false, false, false, false, false><<<gemmGrid, 256, 0, stream>>>(
          hcur, gW + (size_t)l * 64 * 64, xwb, nullptr, nullptr, nullptr, nullptr, N);
      agg_k<<<1024, 256, 0, stream>>>(xwb, dinvT, rpT, epkT, ag, SLOT(t, 2 + l), N);
      bnres_k<<<CDIV(N * 16, 256), 256, 0, stream>>>(ag, hcur, SLOT(t, 2 + l), gg + l * 64, gbe + l * 64, N);
    }

    // post MLP (fp32 raw into ag) -> BN -> H[t]
    gemm_mfma<64, 64, false, false, true, false, true><<<gemmGrid, 256, 0, stream>>>(
        hcur, Wp, ag, nullptr, nullptr, nullptr, SLOT(t, 5), N);
    bnbf_k<<<CDIV(N * 16, 256), 256, 0, stream>>>(ag, H + (size_t)t * N * 64, SLOT(t, 5), gp, bep, N, 64);
  }

  // ================= GRU over T steps =================
  hipMemsetAsync(hA, 0, (size_t)N * 64 * 2, stream);
  ushort* hprev = hA;
  ushort* hnext = hB;
  for (int t = 0; t < T; ++t) {
    gemm_mfma<64, 192, true, false, false, false, false><<<gemmGrid, 256, 0, stream>>>(
        H + (size_t)t * N * 64, Wih, gi, nullptr, nullptr, nullptr, nullptr, N);
    gemm_mfma<64, 192, true, false, false, false, false><<<gemmGrid, 256, 0, stream>>>(
        hprev, Whh, gh, nullptr, nullptr, nullptr, nullptr, N);
    gate_k<<<CDIV(N * 64, 256), 256, 0, stream>>>(gi, gh, bih, bhh, hprev, hnext, N);
    ushort* tmp = hprev; hprev = hnext; hnext = tmp;
  }
  // after 8 steps hprev == hA (at arena+38.4MB; uf occupies [0,25.6MB) - no overlap)

  // ================= classifier =================
  gemm_mfma<64, 128, false, false, true, false, true><<<gemmGrid, 256, 0, stream>>>(
      hprev, Wc1, uf, nullptr, nullptr, nullptr, statsA + 48 * 256, N);
  final_k<<<CDIV(N * 4, 256), 256, 0, stream>>>(uf, statsA + 48 * 256, gc, bec, Wc2, bc2, out, N);
}

// Round 7
// 3947.581 us; speedup vs baseline: 2.3531x; 1.2779x over previous
//
#include <hip/hip_runtime.h>
#include <hip/hip_bf16.h>
#include <cstddef>

#define CDIV(a,b) (((a)+(b)-1)/(b))

static constexpr float BN_EPS = 1e-5f;

typedef __attribute__((ext_vector_type(8))) short short8v;   // 8 bf16 (4 VGPRs)
typedef __attribute__((ext_vector_type(4))) float f32x4;

__device__ inline ushort f2bf(float x) {
  unsigned u = __float_as_uint(x);
  unsigned r = (u + 0x7fffu + ((u >> 16) & 1u)) >> 16;
  return (ushort)r;
}
__device__ inline float bf2f(ushort h) {
  return __uint_as_float(((unsigned)h) << 16);
}

// ---------------- weight fragment prep (once per launch) ----------------
// Wf layout: Wf[((mt*NKC+kc)*64 + lane)*8 + j], lane=((kr>>3)<<4)|(m&15), j=kr&7
template<int K, int M, bool TRANSW>
__global__ void wprep_k(const float* __restrict__ W, ushort* __restrict__ Wf) {
  constexpr int NKC = K / 32;
  for (int i = threadIdx.x; i < K * M; i += 256) {
    int k, m;
    if (TRANSW) { m = i / K; k = i - m * K; }
    else        { k = i / M; m = i - k * M; }
    float wv = W[i];
    int mt = m >> 4, ml = m & 15, kc = k >> 5, kr = k & 31;
    int lane = ((kr >> 3) << 4) | ml;
    int j = kr & 7;
    Wf[(size_t)((mt * NKC + kc) * 64 + lane) * 8 + j] = f2bf(wv);
  }
}

// =====================================================================
// bf16 MFMA GEMM v2: C[N,M] = Aeff[N,K] @ Weff[K,M]  (fp32 accumulate)
// Wf: prebuilt fragment-ordered bf16 weights.
// AMODE: 0 = A bf16 plain; 1 = A fp32 plain; 2 = Aeff = ReLU(BN(A fp32));
//        3 = Aeff = base(bf16) + ReLU(BN(A2 fp32))   [residual]
// SIDE : write Aeff (bf16) to `side` during staging (modes 2/3).
// FSTAT: per-column sum/sumsq of fp32 accumulators -> oStat[c], oStat[128+c].
// OUTF32: write fp32 C, else bf16.
// GATE : GRU epilogue (M=192): reads gi,bih,bhh,hprev(=Ain), writes hnext[N,64];
//        no C write, no FSTAT.
// NOTE: bnSc/bnSh are produced by a thread subset and consumed by ALL threads
// in A-staging -> the __syncthreads() after their computation is REQUIRED.
// =====================================================================
template<int K, int M, int AMODE, bool FSTAT, bool OUTF32, bool SIDE, bool GATE>
__global__ __launch_bounds__(256)
void gemm2(const void* __restrict__ Ain, const float* __restrict__ A2,
           const ushort* __restrict__ Wf, void* __restrict__ Cout,
           ushort* __restrict__ side,
           const float* __restrict__ aStat, const float* __restrict__ aG,
           const float* __restrict__ aB, float* __restrict__ oStat,
           const ushort* __restrict__ gi, const float* __restrict__ bih,
           const float* __restrict__ bhh, ushort* __restrict__ hnext, int N) {
  constexpr int BM = 128;
  constexpr int NKC = K / 32;
  constexpr int NMT = M / 16;
  constexpr bool BN = (AMODE >= 2);
  __shared__ __align__(16) ushort As[BM * K];
  __shared__ __align__(16) ushort WfL[M * K];
  __shared__ float bnSc[BN ? K : 1];
  __shared__ float bnSh[BN ? K : 1];
  __shared__ float redS[FSTAT ? M : 1];
  __shared__ float redQ[FSTAT ? M : 1];
  __shared__ float bihL[GATE ? 192 : 1];
  __shared__ float bhhL[GATE ? 192 : 1];
  const int tid = threadIdx.x;
  const int row0 = blockIdx.x * BM;

  // ---- W fragments -> LDS (flat vector copy) ----
  for (int i = tid; i < K * M / 8; i += 256)
    ((short8v*)WfL)[i] = ((const short8v*)Wf)[i];
  if (GATE) {
    if (tid < 192) { bihL[tid] = bih[tid]; bhhL[tid] = bhh[tid]; }
  }
  if (BN) {
    float invN = 1.f / (float)N;
    for (int i = tid; i < K; i += 256) {
      float mn = aStat[i] * invN;
      float vr = fmaxf(aStat[128 + i] * invN - mn * mn, 0.f);
      float sc = aG[i] * rsqrtf(vr + BN_EPS);
      bnSc[i] = sc;
      bnSh[i] = aB[i] - mn * sc;
    }
    __syncthreads();  // bnSc/bnSh must be visible to all threads before A-staging
  }
  if (FSTAT) {
    if (tid < M) { redS[tid] = 0.f; redQ[tid] = 0.f; }
  }

  // ---- A -> XOR-swizzled bf16 LDS ----
  {
    const float* Af = (const float*)Ain;
    const ushort* Ab = (const ushort*)Ain;
    for (int i = tid; i < BM * K / 4; i += 256) {
      int row = (i * 4) / K, k0 = (i * 4) % K;
      int grow = row0 + row;
      ushort h4[4] = {0, 0, 0, 0};
      if (AMODE == 0) {
        if (grow < N) *(ushort4*)h4 = *(const ushort4*)&Ab[(size_t)grow * K + k0];
      } else if (AMODE == 1) {
        float vv[4] = {0.f, 0.f, 0.f, 0.f};
        if (grow < N) *(float4*)vv = *(const float4*)&Af[(size_t)grow * K + k0];
#pragma unroll
        for (int c = 0; c < 4; ++c) h4[c] = f2bf(vv[c]);
      } else {
        float vv[4] = {0.f, 0.f, 0.f, 0.f};
        if (grow < N) {
          float rw[4];
          if (AMODE == 2) *(float4*)rw = *(const float4*)&Af[(size_t)grow * K + k0];
          else            *(float4*)rw = *(const float4*)&A2[(size_t)grow * K + k0];
          ushort b4[4];
          if (AMODE == 3) *(ushort4*)b4 = *(const ushort4*)&Ab[(size_t)grow * K + k0];
#pragma unroll
          for (int c = 0; c < 4; ++c) {
            float v = fmaxf(fmaf(rw[c], bnSc[k0 + c], bnSh[k0 + c]), 0.f);
            vv[c] = (AMODE == 3) ? bf2f(b4[c]) + v : v;
            h4[c] = f2bf(vv[c]);
          }
          if (SIDE) *(ushort4*)&side[(size_t)grow * K + k0] = *(ushort4*)h4;
        }
      }
      unsigned off = ((unsigned)(row * K + k0) * 2u) ^ (((unsigned)(row & 7)) << 4);
      *(ushort4*)((char*)As + off) = *(ushort4*)h4;
    }
  }
  __syncthreads();

  // ---- MFMA compute ----
  const int wvi = tid >> 6, lane = tid & 63;
  const int lrow = lane & 15, lkg = lane >> 4;

  short8v af[2][NKC];
#pragma unroll
  for (int rt = 0; rt < 2; ++rt)
#pragma unroll
    for (int kc = 0; kc < NKC; ++kc) {
      int row = wvi * 32 + rt * 16 + lrow;
      unsigned off = ((unsigned)(row * K + kc * 32 + lkg * 8) * 2u) ^ (((unsigned)(row & 7)) << 4);
      af[rt][kc] = *(const short8v*)((const char*)As + off);
    }

  f32x4 acc[2][NMT];
#pragma unroll
  for (int rt = 0; rt < 2; ++rt)
#pragma unroll
    for (int mt = 0; mt < NMT; ++mt) acc[rt][mt] = f32x4{0.f, 0.f, 0.f, 0.f};

#pragma unroll
  for (int mt = 0; mt < NMT; ++mt) {
    short8v bf[NKC];
#pragma unroll
    for (int kc = 0; kc < NKC; ++kc)
      bf[kc] = *(const short8v*)&WfL[(size_t)((mt * NKC + kc) * 64 + lane) * 8];
#pragma unroll
    for (int rt = 0; rt < 2; ++rt)
#pragma unroll
      for (int kc = 0; kc < NKC; ++kc)
        acc[rt][mt] = __builtin_amdgcn_mfma_f32_16x16x32_bf16(af[rt][kc], bf[kc], acc[rt][mt], 0, 0, 0);
  }

  if (GATE) {
    // GRU gate epilogue: cols j=mtj*16+lrow; r@mtj, z@mtj+4, g@mtj+8
#pragma unroll
    for (int rt = 0; rt < 2; ++rt)
#pragma unroll
      for (int i = 0; i < 4; ++i) {
        int grow = row0 + wvi * 32 + rt * 16 + lkg * 4 + i;
        if (grow < N) {
          const ushort* gip = gi + (size_t)grow * 192;
          const ushort* hpp = (const ushort*)Ain + (size_t)grow * 64;
#pragma unroll
          for (int mtj = 0; mtj < 4; ++mtj) {
            int j = mtj * 16 + lrow;
            float ir = bf2f(gip[j]) + bihL[j];
            float iz = bf2f(gip[64 + j]) + bihL[64 + j];
            float ig = bf2f(gip[128 + j]) + bihL[128 + j];
            float hr = acc[rt][mtj][i] + bhhL[j];
            float hz = acc[rt][mtj + 4][i] + bhhL[64 + j];
            float hg = acc[rt][mtj + 8][i] + bhhL[128 + j];
            float r = 1.f / (1.f + expf(-(ir + hr)));
            float z = 1.f / (1.f + expf(-(iz + hz)));
            float ng = tanhf(ig + r * hg);
            float hn = (1.f - z) * ng + z * bf2f(hpp[j]);
            hnext[(size_t)grow * 64 + j] = f2bf(hn);
          }
        }
      }
    return;
  }

  // ---- C write, C/D layout: col=lane&15, row=(lane>>4)*4+i ----
#pragma unroll
  for (int rt = 0; rt < 2; ++rt)
#pragma unroll
    for (int mt = 0; mt < NMT; ++mt) {
#pragma unroll
      for (int i = 0; i < 4; ++i) {
        int grow = row0 + wvi * 32 + rt * 16 + lkg * 4 + i;
        if (grow < N) {
          if (OUTF32) ((float*)Cout)[(size_t)grow * M + mt * 16 + lrow] = acc[rt][mt][i];
          else        ((ushort*)Cout)[(size_t)grow * M + mt * 16 + lrow] = f2bf(acc[rt][mt][i]);
        }
      }
    }

  // ---- fused column stats from exact fp32 accumulators ----
  if (FSTAT) {
#pragma unroll
    for (int mt = 0; mt < NMT; ++mt) {
      float s = 0.f, q = 0.f;
#pragma unroll
      for (int rt = 0; rt < 2; ++rt)
#pragma unroll
        for (int i = 0; i < 4; ++i) {
          int grow = row0 + wvi * 32 + rt * 16 + lkg * 4 + i;
          if (grow < N) { float v = acc[rt][mt][i]; s += v; q += v * v; }
        }
      s += __shfl_xor(s, 16); s += __shfl_xor(s, 32);
      q += __shfl_xor(q, 16); q += __shfl_xor(q, 32);
      if (lkg == 0) {
        atomicAdd(&redS[mt * 16 + lrow], s);
        atomicAdd(&redQ[mt * 16 + lrow], q);
      }
    }
    __syncthreads();
    if (tid < M) {
      atomicAdd(&oStat[tid], redS[tid]);
      atomicAdd(&oStat[128 + tid], redQ[tid]);
    }
  }
}

// ---------------- BN+ReLU (fp32 raw in -> bf16 normalized out) ----------------
__global__ __launch_bounds__(256) void bnbf_k(const float* __restrict__ X, ushort* __restrict__ Y,
                                              const float* __restrict__ st,
                                              const float* __restrict__ g, const float* __restrict__ be,
                                              int N, int M) {
  int i4 = blockIdx.x * 256 + threadIdx.x;
  int total = N * M / 4;
  if (i4 >= total) return;
  int c0 = (i4 * 4) % M;
  float invN = 1.f / (float)N;
  float xv[4];
  *(float4*)xv = *(const float4*)&X[(size_t)i4 * 4];
  ushort yv[4];
#pragma unroll
  for (int j = 0; j < 4; ++j) {
    int c = c0 + j;
    float mn = st[c] * invN;
    float vr = fmaxf(st[128 + c] * invN - mn * mn, 0.f);
    float sc = g[c] * rsqrtf(vr + BN_EPS);
    float v = (xv[j] - mn) * sc + be[c];
    yv[j] = f2bf(fmaxf(v, 0.f));
  }
  *(ushort4*)&Y[(size_t)i4 * 4] = *(ushort4*)yv;
}

// ---------------- batched graph prep ----------------
__global__ void hist_k(const int* __restrict__ dst, int* __restrict__ cnt, int* __restrict__ rank,
                       int TE, int N, int E) {
  int i = blockIdx.x * 256 + threadIdx.x;
  if (i >= TE) return;
  int t = i / E;
  rank[i] = atomicAdd(&cnt[t * N + dst[i]], 1);
}
__global__ __launch_bounds__(256) void scan1_k(const int* __restrict__ in, int* __restrict__ incl,
                                               int* __restrict__ bsum, int n) {
  int t = blockIdx.y;
  const int* inp = in + (size_t)t * n;
  int* ip = incl + (size_t)t * n;
  int i = blockIdx.x * 256 + threadIdx.x;
  int v = (i < n) ? inp[i] : 0;
  int lane = threadIdx.x & 63;
  int sidx = threadIdx.x >> 6;
  int sv = v;
  for (int off = 1; off < 64; off <<= 1) {
    int tt = __shfl_up(sv, off, 64);
    if (lane >= off) sv += tt;
  }
  __shared__ int wsum[4];
  if (lane == 63) wsum[sidx] = sv;
  __syncthreads();
  int add = 0;
  for (int w = 0; w < sidx; ++w) add += wsum[w];
  sv += add;
  if (i < n) ip[i] = sv;
  if (threadIdx.x == 255) bsum[t * 256 + blockIdx.x] = sv;
}
__global__ __launch_bounds__(256) void scan2_k(int* __restrict__ bsum, int nb) {
  int t = blockIdx.y;
  int* bp = bsum + t * 256;
  int i = threadIdx.x;
  int v = (i < nb) ? bp[i] : 0;
  int lane = threadIdx.x & 63;
  int sidx = threadIdx.x >> 6;
  int sv = v;
  for (int off = 1; off < 64; off <<= 1) {
    int tt = __shfl_up(sv, off, 64);
    if (lane >= off) sv += tt;
  }
  __shared__ int wsum[4];
  if (lane == 63) wsum[sidx] = sv;
  __syncthreads();
  int add = 0;
  for (int w = 0; w < sidx; ++w) add += wsum[w];
  sv += add;
  if (i < nb) bp[i] = sv;
}
__global__ void scan3_k(const int* __restrict__ incl, const int* __restrict__ cnt,
                        const int* __restrict__ bsum, int* __restrict__ rowptr, int n, int E) {
  int t = blockIdx.y;
  int i = blockIdx.x * 256 + threadIdx.x;
  int* rp = rowptr + (size_t)t * (n + 1);
  if (i < n) {
    int v = incl[(size_t)t * n + i] - cnt[(size_t)t * n + i] +
            (blockIdx.x ? bsum[t * 256 + blockIdx.x - 1] : 0);
    rp[i] = v;
  }
  if (i == 0) rp[n] = E;
}
__global__ void scat_k(const int* __restrict__ src, const int* __restrict__ dst,
                       const float* __restrict__ w, const int* __restrict__ rank,
                       const int* __restrict__ rowptr, int2* __restrict__ epk,
                       int TE, int N1, int E) {
  int i = blockIdx.x * 256 + threadIdx.x;
  if (i >= TE) return;
  int t = i / E;
  int slot = rowptr[(size_t)t * N1 + dst[i]] + rank[i];
  epk[(size_t)t * E + slot] = make_int2(src[i], __float_as_int(w[i]));
}
__global__ void deg_k(const int2* __restrict__ epk, const int* __restrict__ rowptr,
                      float* __restrict__ dinv, int TN, int N, int N1, int E) {
  int i = blockIdx.x * 256 + threadIdx.x;
  if (i >= TN) return;
  int t = i / N, n = i - t * N;
  const int* rp = rowptr + (size_t)t * N1;
  const int2* ep = epk + (size_t)t * E;
  float s = 1.f;  // self loop
  int b = rp[n], e = rp[n + 1];
  for (int j = b; j < e; ++j) s += __int_as_float(ep[j].y);
  dinv[i] = rsqrtf(s);
}
__global__ void norm_k(int2* __restrict__ epk, const int* __restrict__ rowptr,
                       const float* __restrict__ dinv, int TN, int N, int N1, int E) {
  int i = blockIdx.x * 256 + threadIdx.x;
  if (i >= TN) return;
  int t = i / N, n = i - t * N;
  const int* rp = rowptr + (size_t)t * N1;
  const float* dv = dinv + (size_t)t * N;
  int2* ep = epk + (size_t)t * E;
  float dn = dv[n];
  int b = rp[n], e = rp[n + 1];
  for (int j = b; j < e; ++j) {
    int2 ed = ep[j];
    ep[j].y = __float_as_int(dv[ed.x] * __int_as_float(ed.y) * dn);
  }
}

// ---------------- GCN aggregation (bf16 gather) + fused fp32 stats ----------------
__global__ __launch_bounds__(256) void agg_k(const ushort* __restrict__ xw, const float* __restrict__ dinv,
                                             const int* __restrict__ rowptr, const int2* __restrict__ epk,
                                             float* __restrict__ ag, float* __restrict__ oStat, int N) {
  __shared__ float redS[64], redQ[64];
  if (threadIdx.x < 64) { redS[threadIdx.x] = 0.f; redQ[threadIdx.x] = 0.f; }
  __syncthreads();
  int f = threadIdx.x & 63;
  int wvl = threadIdx.x >> 6;
  int stride = gridDim.x * 4;
  float s = 0.f, q = 0.f;
  for (int n = blockIdx.x * 4 + wvl; n < N; n += stride) {
    float di = dinv[n];
    float acc0 = bf2f(xw[(size_t)n * 64 + f]) * di * di;  // self loop
    float acc1 = 0.f;
    int b = rowptr[n], e = rowptr[n + 1];
    int j = b;
    for (; j + 1 < e; j += 2) {
      int2 e0 = epk[j], e1 = epk[j + 1];
      acc0 += bf2f(xw[(size_t)e0.x * 64 + f]) * __int_as_float(e0.y);
      acc1 += bf2f(xw[(size_t)e1.x * 64 + f]) * __int_as_float(e1.y);
    }
    if (j < e) {
      int2 e0 = epk[j];
      acc0 += bf2f(xw[(size_t)e0.x * 64 + f]) * __int_as_float(e0.y);
    }
    float acc = acc0 + acc1;
    ag[(size_t)n * 64 + f] = acc;
    s += acc;
    q += acc * acc;
  }
  atomicAdd(&redS[f], s);
  atomicAdd(&redQ[f], q);
  __syncthreads();
  if (threadIdx.x < 64) {
    atomicAdd(&oStat[threadIdx.x], redS[threadIdx.x]);
    atomicAdd(&oStat[128 + threadIdx.x], redQ[threadIdx.x]);
  }
}

// ---------------- classifier final: BN+ReLU(u fp32) @ Wc2 + bc2 ----------------
__global__ __launch_bounds__(256) void final_k(const float* __restrict__ u, const float* __restrict__ st,
                                               const float* __restrict__ g, const float* __restrict__ be,
                                               const float* __restrict__ Wc2, const float* __restrict__ bc2,
                                               float* __restrict__ out, int N) {
  __shared__ float Wl[512], sc[128], sh[128];
  for (int i = threadIdx.x; i < 512; i += 256) Wl[i] = Wc2[i];
  if (threadIdx.x < 128) {
    int c = threadIdx.x;
    float invN = 1.f / (float)N;
    float mn = st[c] * invN;
    float vr = fmaxf(st[128 + c] * invN - mn * mn, 0.f);
    float s = g[c] * rsqrtf(vr + BN_EPS);
    sc[c] = s;
    sh[c] = be[c] - mn * s;
  }
  __syncthreads();
  int idx = blockIdx.x * 256 + threadIdx.x;
  if (idx >= N * 4) return;
  int n = idx >> 2, c = idx & 3;
  const float* ur = u + (size_t)n * 128;
  float acc = bc2[c];
#pragma unroll 8
  for (int k = 0; k < 128; ++k) {
    float v = fmaxf(fmaf(ur[k], sc[k], sh[k]), 0.f);
    acc = fmaf(v, Wl[k * 4 + c], acc);
  }
  out[idx] = acc;
}

extern "C" void kernel_launch(void* const* d_in, const int* in_sizes, int n_in,
                              void* d_out, int out_size, void* d_ws, size_t ws_size,
                              hipStream_t stream) {
  const float* xs   = (const float*)d_in[0];
  const int*   esrc = (const int*)d_in[1];
  const int*   edst = (const int*)d_in[2];
  const float* ew   = (const float*)d_in[3];
  const float* W1   = (const float*)d_in[4];
  const float* g1   = (const float*)d_in[6];
  const float* be1  = (const float*)d_in[7];
  const float* W2   = (const float*)d_in[8];
  const float* g2   = (const float*)d_in[10];
  const float* be2  = (const float*)d_in[11];
  const float* gW   = (const float*)d_in[12];
  const float* gg   = (const float*)d_in[14];
  const float* gbe  = (const float*)d_in[15];
  const float* Wp   = (const float*)d_in[16];
  const float* gp   = (const float*)d_in[18];
  const float* bep  = (const float*)d_in[19];
  const float* Wih  = (const float*)d_in[20];
  const float* Whh  = (const float*)d_in[21];
  const float* bih  = (const float*)d_in[22];
  const float* bhh  = (const float*)d_in[23];
  const float* Wc1  = (const float*)d_in[24];
  const float* gc   = (const float*)d_in[26];
  const float* bec  = (const float*)d_in[27];
  const float* Wc2  = (const float*)d_in[28];
  const float* bc2  = (const float*)d_in[29];
  float* out = (float*)d_out;

  const int T = 8;
  const int N = in_sizes[0] / (T * 32);
  const int E = in_sizes[1] / T;
  const int TE = T * E, TN = T * N, N1 = N + 1;

  // ---- workspace layout (bytes) ----
  size_t off = 0;
  auto alloc = [&](size_t bytes) { size_t o = off; off += (bytes + 255) & ~(size_t)255; return o; };
  char* base = (char*)d_ws;
  size_t oH      = alloc((size_t)T * N * 64 * 2);   // H bf16 (normalized)
  size_t oEpk    = alloc((size_t)TE * 8);           // packed (src, w/norm)
  size_t oRp     = alloc((size_t)T * N1 * 4);       // rowptr
  size_t oDinv   = alloc((size_t)TN * 4);           // dinv
  size_t oStats  = alloc((size_t)49 * 256 * 4);     // stats slots
  size_t oBsum   = alloc((size_t)T * 256 * 4);      // scan block sums
  size_t oWf     = alloc((size_t)70000 * 2);        // prebuilt weight fragments
  size_t oArena  = alloc((size_t)64 * 1024 * 1024); // phase-shared arena
  if (ws_size < off) return;

  ushort* H     = (ushort*)(base + oH);
  int2*   epk   = (int2*)(base + oEpk);
  int*    rowptr= (int*)(base + oRp);
  float*  dinv  = (float*)(base + oDinv);
  float*  statsA= (float*)(base + oStats);
  int*    bsum  = (int*)(base + oBsum);
  ushort* wfA   = (ushort*)(base + oWf);
  char*   arena = base + oArena;

  // weight fragment offsets (ushort elements)
  ushort* W1f  = wfA;               // 32*128  = 4096
  ushort* W2f  = W1f + 4096;        // 128*64  = 8192
  ushort* gW0f = W2f + 8192;        // 64*64   = 4096
  ushort* gW1f = gW0f + 4096;
  ushort* gW2f = gW1f + 4096;
  ushort* Wpf  = gW2f + 4096;       // 64*64
  ushort* Wihf = Wpf + 4096;        // 64*192  = 12288
  ushort* Whhf = Wihf + 12288;
  ushort* Wc1f = Whhf + 12288;      // 64*128  = 8192  (total 61440)

  // prep-phase arena views
  int* cnt  = (int*)arena;                         // [T*N]
  int* incl = cnt + TN;                            // [T*N]
  int* rank = incl + TN;                           // [T*E]
  // encoder-phase arena views
  float*  y1f  = (float*)arena;                    // [N,128] fp32 raw (also praw)
  float*  hbf  = y1f + (size_t)N * 128;            // [N,64]  fp32 raw
  ushort* hcur = (ushort*)(hbf + (size_t)N * 64);  // [N,64]  bf16 normalized
  ushort* xwb  = hcur + (size_t)N * 64;            // [N,64]  bf16 gather table
  float*  ag   = (float*)(xwb + (size_t)N * 64);   // [N,64]  fp32 raw agg
  // gru/cls-phase arena views
  ushort* gi = (ushort*)arena;                     // [N,192] bf16 ([0,19.2MB))
  ushort* hA = (ushort*)(arena + (size_t)40 * 1024 * 1024);  // [N,64]
  ushort* hB = hA + (size_t)N * 64;
  float*  uf = (float*)arena;                      // [N,128] fp32 ([0,25.6MB), gi dead)

  const int nb = CDIV(N, 256);

#define SLOT(t, j) (statsA + ((size_t)(t) * 6 + (j)) * 256)

  hipMemsetAsync(statsA, 0, (size_t)49 * 256 * 4, stream);
  hipMemsetAsync(cnt, 0, (size_t)TN * 4, stream);

  // ---- weight fragment prep (once per launch, 9 tiny blocks) ----
  wprep_k<32, 128, false><<<1, 256, 0, stream>>>(W1, W1f);
  wprep_k<128, 64, false><<<1, 256, 0, stream>>>(W2, W2f);
  wprep_k<64, 64, false><<<1, 256, 0, stream>>>(gW, gW0f);
  wprep_k<64, 64, false><<<1, 256, 0, stream>>>(gW + 4096, gW1f);
  wprep_k<64, 64, false><<<1, 256, 0, stream>>>(gW + 8192, gW2f);
  wprep_k<64, 64, false><<<1, 256, 0, stream>>>(Wp, Wpf);
  wprep_k<64, 192, true><<<1, 256, 0, stream>>>(Wih, Wihf);
  wprep_k<64, 192, true><<<1, 256, 0, stream>>>(Whh, Whhf);

  // ================= batched graph prep (all T) =================
  hist_k<<<CDIV(TE, 256), 256, 0, stream>>>(edst, cnt, rank, TE, N, E);
  scan1_k<<<dim3(nb, T), 256, 0, stream>>>(cnt, incl, bsum, N);
  scan2_k<<<dim3(1, T), 256, 0, stream>>>(bsum, nb);
  scan3_k<<<dim3(nb, T), 256, 0, stream>>>(incl, cnt, bsum, rowptr, N, E);
  scat_k<<<CDIV(TE, 256), 256, 0, stream>>>(esrc, edst, ew, rank, rowptr, epk, TE, N1, E);
  deg_k<<<CDIV(TN, 256), 256, 0, stream>>>(epk, rowptr, dinv, TN, N, N1, E);
  norm_k<<<CDIV(TN, 256), 256, 0, stream>>>(epk, rowptr, dinv, TN, N, N1, E);
  wprep_k<64, 128, false><<<1, 256, 0, stream>>>(Wc1, Wc1f);

  const int gemmGrid = CDIV(N, 128);
  const float* ncf = nullptr;   // const float* null
  float* nmf = nullptr;         // float* null (oStat)
  ushort* nus = nullptr;        // ushort* null
  const ushort* ncus = nullptr; // const ushort* null

  // ================= encoder over T timesteps =================
  for (int t = 0; t < T; ++t) {
    const float* xt = xs + (size_t)t * N * 32;
    const int* rpT = rowptr + (size_t)t * N1;
    const int2* epkT = epk + (size_t)t * E;
    const float* dinvT = dinv + (size_t)t * N;

    // MLP1: y1f(fp32 raw) = xt @ W1, stats0
    gemm2<32, 128, 1, true, true, false, false><<<gemmGrid, 256, 0, stream>>>(
        xt, ncf, W1f, y1f, nus, ncf, ncf, ncf, SLOT(t, 0),
        ncus, ncf, ncf, nus, N);
    // MLP2: hbf(fp32 raw) = BNReLU(y1f) @ W2, stats1
    gemm2<128, 64, 2, true, true, false, false><<<gemmGrid, 256, 0, stream>>>(
        y1f, ncf, W2f, hbf, nus, SLOT(t, 0), g1, be1, SLOT(t, 1),
        ncus, ncf, ncf, nus, N);
    // GCN0: A = BNReLU(hbf) [-> side hcur], out xwb bf16
    gemm2<64, 64, 2, false, false, true, false><<<gemmGrid, 256, 0, stream>>>(
        hbf, ncf, gW0f, xwb, hcur, SLOT(t, 1), g2, be2, nmf,
        ncus, ncf, ncf, nus, N);
    agg_k<<<1024, 256, 0, stream>>>(xwb, dinvT, rpT, epkT, ag, SLOT(t, 2), N);
    // GCN1: A = hcur + ReLU(BN(ag)) [-> side hcur], out xwb
    gemm2<64, 64, 3, false, false, true, false><<<gemmGrid, 256, 0, stream>>>(
        hcur, ag, gW1f, xwb, hcur, SLOT(t, 2), gg, gbe, nmf,
        ncus, ncf, ncf, nus, N);
    agg_k<<<1024, 256, 0, stream>>>(xwb, dinvT, rpT, epkT, ag, SLOT(t, 3), N);
    // GCN2
    gemm2<64, 64, 3, false, false, true, false><<<gemmGrid, 256, 0, stream>>>(
        hcur, ag, gW2f, xwb, hcur, SLOT(t, 3), gg + 64, gbe + 64, nmf,
        ncus, ncf, ncf, nus, N);
    agg_k<<<1024, 256, 0, stream>>>(xwb, dinvT, rpT, epkT, ag, SLOT(t, 4), N);
    // POST: A = hcur + ReLU(BN(ag)), out praw(y1f) fp32 + stats5
    gemm2<64, 64, 3, true, true, false, false><<<gemmGrid, 256, 0, stream>>>(
        hcur, ag, Wpf, y1f, nus, SLOT(t, 4), gg + 128, gbe + 128, SLOT(t, 5),
        ncus, ncf, ncf, nus, N);
    bnbf_k<<<CDIV(N * 16, 256), 256, 0, stream>>>(y1f, H + (size_t)t * N * 64, SLOT(t, 5), gp, bep, N, 64);
  }

  // ================= GRU over T steps =================
  hipMemsetAsync(hA, 0, (size_t)N * 64 * 2, stream);
  ushort* hprev = hA;
  ushort* hnext = hB;
  for (int t = 0; t < T; ++t) {
    // gi = H[t] @ Wih^T  (bf16 out, no bias - folded into gate)
    gemm2<64, 192, 0, false, false, false, false><<<gemmGrid, 256, 0, stream>>>(
        H + (size_t)t * N * 64, ncf, Wihf, gi, nus, ncf, ncf, ncf, nmf,
        ncus, ncf, ncf, nus, N);
    // gh = hprev @ Whh^T + fused GRU gate -> hnext
    gemm2<64, 192, 0, false, false, false, true><<<gemmGrid, 256, 0, stream>>>(
        hprev, ncf, Whhf, (void*)nullptr, nus, ncf, ncf, ncf, nmf,
        gi, bih, bhh, hnext, N);
    ushort* tmp = hprev; hprev = hnext; hnext = tmp;
  }
  // after 8 steps hprev == hA (arena+40MB; uf occupies [0,25.6MB) - no overlap)

  // ================= classifier =================
  gemm2<64, 128, 0, true, true, false, false><<<gemmGrid, 256, 0, stream>>>(
      hprev, ncf, Wc1f, uf, nus, ncf, ncf, ncf, statsA + 48 * 256,
      ncus, ncf, ncf, nus, N);
  final_k<<<CDIV(N * 4, 256), 256, 0, stream>>>(uf, statsA + 48 * 256, gc, bec, Wc2, bc2, out, N);
}

// Round 8
// 3583.452 us; speedup vs baseline: 2.5922x; 1.1016x over previous
//
#include <hip/hip_runtime.h>
#include <hip/hip_bf16.h>
#include <cstddef>

#define CDIV(a,b) (((a)+(b)-1)/(b))

static constexpr float BN_EPS = 1e-5f;

typedef __attribute__((ext_vector_type(8))) short short8v;   // 8 bf16 (4 VGPRs)
typedef __attribute__((ext_vector_type(4))) float f32x4;

__device__ inline ushort f2bf(float x) {
  unsigned u = __float_as_uint(x);
  unsigned r = (u + 0x7fffu + ((u >> 16) & 1u)) >> 16;
  return (ushort)r;
}
__device__ inline float bf2f(ushort h) {
  return __uint_as_float(((unsigned)h) << 16);
}

// ---------------- weight fragment prep (once per launch) ----------------
// Wf layout: Wf[((mt*NKC+kc)*64 + lane)*8 + j], lane=((kr>>3)<<4)|(m&15), j=kr&7
template<int K, int M, bool TRANSW>
__global__ void wprep_k(const float* __restrict__ W, ushort* __restrict__ Wf) {
  constexpr int NKC = K / 32;
  for (int i = threadIdx.x; i < K * M; i += 256) {
    int k, m;
    if (TRANSW) { m = i / K; k = i - m * K; }
    else        { k = i / M; m = i - k * M; }
    float wv = W[i];
    int mt = m >> 4, ml = m & 15, kc = k >> 5, kr = k & 31;
    int lane = ((kr >> 3) << 4) | ml;
    int j = kr & 7;
    Wf[(size_t)((mt * NKC + kc) * 64 + lane) * 8 + j] = f2bf(wv);
  }
}

// =====================================================================
// bf16 MFMA GEMM v2 (same as round 7, passing)
// =====================================================================
template<int K, int M, int AMODE, bool FSTAT, bool OUTF32, bool SIDE, bool GATE>
__global__ __launch_bounds__(256)
void gemm2(const void* __restrict__ Ain, const float* __restrict__ A2,
           const ushort* __restrict__ Wf, void* __restrict__ Cout,
           ushort* __restrict__ side,
           const float* __restrict__ aStat, const float* __restrict__ aG,
           const float* __restrict__ aB, float* __restrict__ oStat,
           const ushort* __restrict__ gi, const float* __restrict__ bih,
           const float* __restrict__ bhh, ushort* __restrict__ hnext, int N) {
  constexpr int BM = 128;
  constexpr int NKC = K / 32;
  constexpr int NMT = M / 16;
  constexpr bool BN = (AMODE >= 2);
  __shared__ __align__(16) ushort As[BM * K];
  __shared__ __align__(16) ushort WfL[M * K];
  __shared__ float bnSc[BN ? K : 1];
  __shared__ float bnSh[BN ? K : 1];
  __shared__ float redS[FSTAT ? M : 1];
  __shared__ float redQ[FSTAT ? M : 1];
  __shared__ float bihL[GATE ? 192 : 1];
  __shared__ float bhhL[GATE ? 192 : 1];
  const int tid = threadIdx.x;
  const int row0 = blockIdx.x * BM;

  for (int i = tid; i < K * M / 8; i += 256)
    ((short8v*)WfL)[i] = ((const short8v*)Wf)[i];
  if (GATE) {
    if (tid < 192) { bihL[tid] = bih[tid]; bhhL[tid] = bhh[tid]; }
  }
  if (BN) {
    float invN = 1.f / (float)N;
    for (int i = tid; i < K; i += 256) {
      float mn = aStat[i] * invN;
      float vr = fmaxf(aStat[128 + i] * invN - mn * mn, 0.f);
      float sc = aG[i] * rsqrtf(vr + BN_EPS);
      bnSc[i] = sc;
      bnSh[i] = aB[i] - mn * sc;
    }
    __syncthreads();  // bnSc/bnSh must be visible to all threads before A-staging
  }
  if (FSTAT) {
    if (tid < M) { redS[tid] = 0.f; redQ[tid] = 0.f; }
  }

  {
    const float* Af = (const float*)Ain;
    const ushort* Ab = (const ushort*)Ain;
    for (int i = tid; i < BM * K / 4; i += 256) {
      int row = (i * 4) / K, k0 = (i * 4) % K;
      int grow = row0 + row;
      ushort h4[4] = {0, 0, 0, 0};
      if (AMODE == 0) {
        if (grow < N) *(ushort4*)h4 = *(const ushort4*)&Ab[(size_t)grow * K + k0];
      } else if (AMODE == 1) {
        float vv[4] = {0.f, 0.f, 0.f, 0.f};
        if (grow < N) *(float4*)vv = *(const float4*)&Af[(size_t)grow * K + k0];
#pragma unroll
        for (int c = 0; c < 4; ++c) h4[c] = f2bf(vv[c]);
      } else {
        float vv[4] = {0.f, 0.f, 0.f, 0.f};
        if (grow < N) {
          float rw[4];
          if (AMODE == 2) *(float4*)rw = *(const float4*)&Af[(size_t)grow * K + k0];
          else            *(float4*)rw = *(const float4*)&A2[(size_t)grow * K + k0];
          ushort b4[4];
          if (AMODE == 3) *(ushort4*)b4 = *(const ushort4*)&Ab[(size_t)grow * K + k0];
#pragma unroll
          for (int c = 0; c < 4; ++c) {
            float v = fmaxf(fmaf(rw[c], bnSc[k0 + c], bnSh[k0 + c]), 0.f);
            vv[c] = (AMODE == 3) ? bf2f(b4[c]) + v : v;
            h4[c] = f2bf(vv[c]);
          }
          if (SIDE) *(ushort4*)&side[(size_t)grow * K + k0] = *(ushort4*)h4;
        }
      }
      unsigned off = ((unsigned)(row * K + k0) * 2u) ^ (((unsigned)(row & 7)) << 4);
      *(ushort4*)((char*)As + off) = *(ushort4*)h4;
    }
  }
  __syncthreads();

  const int wvi = tid >> 6, lane = tid & 63;
  const int lrow = lane & 15, lkg = lane >> 4;

  short8v af[2][NKC];
#pragma unroll
  for (int rt = 0; rt < 2; ++rt)
#pragma unroll
    for (int kc = 0; kc < NKC; ++kc) {
      int row = wvi * 32 + rt * 16 + lrow;
      unsigned off = ((unsigned)(row * K + kc * 32 + lkg * 8) * 2u) ^ (((unsigned)(row & 7)) << 4);
      af[rt][kc] = *(const short8v*)((const char*)As + off);
    }

  f32x4 acc[2][NMT];
#pragma unroll
  for (int rt = 0; rt < 2; ++rt)
#pragma unroll
    for (int mt = 0; mt < NMT; ++mt) acc[rt][mt] = f32x4{0.f, 0.f, 0.f, 0.f};

#pragma unroll
  for (int mt = 0; mt < NMT; ++mt) {
    short8v bf[NKC];
#pragma unroll
    for (int kc = 0; kc < NKC; ++kc)
      bf[kc] = *(const short8v*)&WfL[(size_t)((mt * NKC + kc) * 64 + lane) * 8];
#pragma unroll
    for (int rt = 0; rt < 2; ++rt)
#pragma unroll
      for (int kc = 0; kc < NKC; ++kc)
        acc[rt][mt] = __builtin_amdgcn_mfma_f32_16x16x32_bf16(af[rt][kc], bf[kc], acc[rt][mt], 0, 0, 0);
  }

  if (GATE) {
#pragma unroll
    for (int rt = 0; rt < 2; ++rt)
#pragma unroll
      for (int i = 0; i < 4; ++i) {
        int grow = row0 + wvi * 32 + rt * 16 + lkg * 4 + i;
        if (grow < N) {
          const ushort* gip = gi + (size_t)grow * 192;
          const ushort* hpp = (const ushort*)Ain + (size_t)grow * 64;
#pragma unroll
          for (int mtj = 0; mtj < 4; ++mtj) {
            int j = mtj * 16 + lrow;
            float ir = bf2f(gip[j]) + bihL[j];
            float iz = bf2f(gip[64 + j]) + bihL[64 + j];
            float ig = bf2f(gip[128 + j]) + bihL[128 + j];
            float hr = acc[rt][mtj][i] + bhhL[j];
            float hz = acc[rt][mtj + 4][i] + bhhL[64 + j];
            float hg = acc[rt][mtj + 8][i] + bhhL[128 + j];
            float r = 1.f / (1.f + expf(-(ir + hr)));
            float z = 1.f / (1.f + expf(-(iz + hz)));
            float ng = tanhf(ig + r * hg);
            float hn = (1.f - z) * ng + z * bf2f(hpp[j]);
            hnext[(size_t)grow * 64 + j] = f2bf(hn);
          }
        }
      }
    return;
  }

#pragma unroll
  for (int rt = 0; rt < 2; ++rt)
#pragma unroll
    for (int mt = 0; mt < NMT; ++mt) {
#pragma unroll
      for (int i = 0; i < 4; ++i) {
        int grow = row0 + wvi * 32 + rt * 16 + lkg * 4 + i;
        if (grow < N) {
          if (OUTF32) ((float*)Cout)[(size_t)grow * M + mt * 16 + lrow] = acc[rt][mt][i];
          else        ((ushort*)Cout)[(size_t)grow * M + mt * 16 + lrow] = f2bf(acc[rt][mt][i]);
        }
      }
    }

  if (FSTAT) {
#pragma unroll
    for (int mt = 0; mt < NMT; ++mt) {
      float s = 0.f, q = 0.f;
#pragma unroll
      for (int rt = 0; rt < 2; ++rt)
#pragma unroll
        for (int i = 0; i < 4; ++i) {
          int grow = row0 + wvi * 32 + rt * 16 + lkg * 4 + i;
          if (grow < N) { float v = acc[rt][mt][i]; s += v; q += v * v; }
        }
      s += __shfl_xor(s, 16); s += __shfl_xor(s, 32);
      q += __shfl_xor(q, 16); q += __shfl_xor(q, 32);
      if (lkg == 0) {
        atomicAdd(&redS[mt * 16 + lrow], s);
        atomicAdd(&redQ[mt * 16 + lrow], q);
      }
    }
    __syncthreads();
    if (tid < M) {
      atomicAdd(&oStat[tid], redS[tid]);
      atomicAdd(&oStat[128 + tid], redQ[tid]);
    }
  }
}

// ---------------- BN+ReLU (fp32 raw in -> bf16 normalized out) ----------------
__global__ __launch_bounds__(256) void bnbf_k(const float* __restrict__ X, ushort* __restrict__ Y,
                                              const float* __restrict__ st,
                                              const float* __restrict__ g, const float* __restrict__ be,
                                              int N, int M) {
  int i4 = blockIdx.x * 256 + threadIdx.x;
  int total = N * M / 4;
  if (i4 >= total) return;
  int c0 = (i4 * 4) % M;
  float invN = 1.f / (float)N;
  float xv[4];
  *(float4*)xv = *(const float4*)&X[(size_t)i4 * 4];
  ushort yv[4];
#pragma unroll
  for (int j = 0; j < 4; ++j) {
    int c = c0 + j;
    float mn = st[c] * invN;
    float vr = fmaxf(st[128 + c] * invN - mn * mn, 0.f);
    float sc = g[c] * rsqrtf(vr + BN_EPS);
    float v = (xv[j] - mn) * sc + be[c];
    yv[j] = f2bf(fmaxf(v, 0.f));
  }
  *(ushort4*)&Y[(size_t)i4 * 4] = *(ushort4*)yv;
}

// ---------------- batched graph prep (T-partitioned: t = blockIdx.x & 7 for XCD-L2 locality) ----------------
__global__ void hist_k(const int* __restrict__ dst, int* __restrict__ cnt, int* __restrict__ rank,
                       int N, int E) {
  int t = blockIdx.x & 7;
  int e = (blockIdx.x >> 3) * 256 + threadIdx.x;
  if (e >= E) return;
  size_t i = (size_t)t * E + e;
  rank[i] = atomicAdd(&cnt[t * N + dst[i]], 1);
}
__global__ __launch_bounds__(256) void scan1_k(const int* __restrict__ in, int* __restrict__ incl,
                                               int* __restrict__ bsum, int n) {
  int t = blockIdx.y;
  const int* inp = in + (size_t)t * n;
  int* ip = incl + (size_t)t * n;
  int i = blockIdx.x * 256 + threadIdx.x;
  int v = (i < n) ? inp[i] : 0;
  int lane = threadIdx.x & 63;
  int sidx = threadIdx.x >> 6;
  int sv = v;
  for (int off = 1; off < 64; off <<= 1) {
    int tt = __shfl_up(sv, off, 64);
    if (lane >= off) sv += tt;
  }
  __shared__ int wsum[4];
  if (lane == 63) wsum[sidx] = sv;
  __syncthreads();
  int add = 0;
  for (int w = 0; w < sidx; ++w) add += wsum[w];
  sv += add;
  if (i < n) ip[i] = sv;
  if (threadIdx.x == 255) bsum[t * 256 + blockIdx.x] = sv;
}
__global__ __launch_bounds__(256) void scan2_k(int* __restrict__ bsum, int nb) {
  int t = blockIdx.y;
  int* bp = bsum + t * 256;
  int i = threadIdx.x;
  int v = (i < nb) ? bp[i] : 0;
  int lane = threadIdx.x & 63;
  int sidx = threadIdx.x >> 6;
  int sv = v;
  for (int off = 1; off < 64; off <<= 1) {
    int tt = __shfl_up(sv, off, 64);
    if (lane >= off) sv += tt;
  }
  __shared__ int wsum[4];
  if (lane == 63) wsum[sidx] = sv;
  __syncthreads();
  int add = 0;
  for (int w = 0; w < sidx; ++w) add += wsum[w];
  sv += add;
  if (i < nb) bp[i] = sv;
}
__global__ void scan3_k(const int* __restrict__ incl, const int* __restrict__ cnt,
                        const int* __restrict__ bsum, int* __restrict__ rowptr, int n, int E) {
  int t = blockIdx.y;
  int i = blockIdx.x * 256 + threadIdx.x;
  int* rp = rowptr + (size_t)t * (n + 1);
  if (i < n) {
    int v = incl[(size_t)t * n + i] - cnt[(size_t)t * n + i] +
            (blockIdx.x ? bsum[t * 256 + blockIdx.x - 1] : 0);
    rp[i] = v;
  }
  if (i == 0) rp[n] = E;
}
__global__ void scat_k(const int* __restrict__ src, const int* __restrict__ dst,
                       const float* __restrict__ w, const int* __restrict__ rank,
                       const int* __restrict__ rowptr, int2* __restrict__ epk,
                       int N1, int E) {
  int t = blockIdx.x & 7;
  int e = (blockIdx.x >> 3) * 256 + threadIdx.x;
  if (e >= E) return;
  size_t i = (size_t)t * E + e;
  int slot = rowptr[(size_t)t * N1 + dst[i]] + rank[i];
  epk[(size_t)t * E + slot] = make_int2(src[i], __float_as_int(w[i]));
}
__global__ void deg_k(const int2* __restrict__ epk, const int* __restrict__ rowptr,
                      float* __restrict__ dinv, int N, int N1, int E) {
  int t = blockIdx.x & 7;
  int n = (blockIdx.x >> 3) * 256 + threadIdx.x;
  if (n >= N) return;
  const int* rp = rowptr + (size_t)t * N1;
  const int2* ep = epk + (size_t)t * E;
  float s = 1.f;  // self loop
  int b = rp[n], e = rp[n + 1];
  for (int j = b; j < e; ++j) s += __int_as_float(ep[j].y);
  dinv[(size_t)t * N + n] = rsqrtf(s);
}
__global__ void norm_k(int2* __restrict__ epk, const int* __restrict__ rowptr,
                       const float* __restrict__ dinv, int N, int N1, int E) {
  int t = blockIdx.x & 7;
  int n = (blockIdx.x >> 3) * 256 + threadIdx.x;
  if (n >= N) return;
  const int* rp = rowptr + (size_t)t * N1;
  const float* dv = dinv + (size_t)t * N;
  int2* ep = epk + (size_t)t * E;
  float dn = dv[n];
  int b = rp[n], e = rp[n + 1];
  for (int j = b; j < e; ++j) {
    int2 ed = ep[j];
    ep[j].y = __float_as_int(dv[ed.x] * __int_as_float(ed.y) * dn);
  }
}

// ---------------- GCN aggregation (bf16 gather, int4 dual-edge loads) + fused fp32 stats ----------------
__global__ __launch_bounds__(256) void agg_k(const ushort* __restrict__ xw, const float* __restrict__ dinv,
                                             const int* __restrict__ rowptr, const int2* __restrict__ epk,
                                             float* __restrict__ ag, float* __restrict__ oStat, int N) {
  __shared__ float redS[64], redQ[64];
  if (threadIdx.x < 64) { redS[threadIdx.x] = 0.f; redQ[threadIdx.x] = 0.f; }
  __syncthreads();
  int f = threadIdx.x & 63;
  int wvl = threadIdx.x >> 6;
  int stride = gridDim.x * 4;
  float s = 0.f, q = 0.f;
  for (int n = blockIdx.x * 4 + wvl; n < N; n += stride) {
    float di = dinv[n];
    float acc0 = bf2f(xw[(size_t)n * 64 + f]) * di * di;  // self loop
    float acc1 = 0.f;
    int b = rowptr[n], e = rowptr[n + 1];
    int j = b;
    if ((j & 1) && j < e) {   // align to 16B for int4 loads
      int2 e0 = epk[j];
      acc1 += bf2f(xw[(size_t)e0.x * 64 + f]) * __int_as_float(e0.y);
      ++j;
    }
    for (; j + 3 < e; j += 4) {
      int4 p01 = *(const int4*)&epk[j];
      int4 p23 = *(const int4*)&epk[j + 2];
      acc0 += bf2f(xw[(size_t)p01.x * 64 + f]) * __int_as_float(p01.y);
      acc1 += bf2f(xw[(size_t)p01.z * 64 + f]) * __int_as_float(p01.w);
      acc0 += bf2f(xw[(size_t)p23.x * 64 + f]) * __int_as_float(p23.y);
      acc1 += bf2f(xw[(size_t)p23.z * 64 + f]) * __int_as_float(p23.w);
    }
    for (; j < e; ++j) {
      int2 e0 = epk[j];
      acc0 += bf2f(xw[(size_t)e0.x * 64 + f]) * __int_as_float(e0.y);
    }
    float acc = acc0 + acc1;
    ag[(size_t)n * 64 + f] = acc;
    s += acc;
    q += acc * acc;
  }
  atomicAdd(&redS[f], s);
  atomicAdd(&redQ[f], q);
  __syncthreads();
  if (threadIdx.x < 64) {
    atomicAdd(&oStat[threadIdx.x], redS[threadIdx.x]);
    atomicAdd(&oStat[128 + threadIdx.x], redQ[threadIdx.x]);
  }
}

// ---------------- classifier final: BN+ReLU(u fp32) @ Wc2 + bc2 ----------------
__global__ __launch_bounds__(256) void final_k(const float* __restrict__ u, const float* __restrict__ st,
                                               const float* __restrict__ g, const float* __restrict__ be,
                                               const float* __restrict__ Wc2, const float* __restrict__ bc2,
                                               float* __restrict__ out, int N) {
  __shared__ float Wl[512], sc[128], sh[128];
  for (int i = threadIdx.x; i < 512; i += 256) Wl[i] = Wc2[i];
  if (threadIdx.x < 128) {
    int c = threadIdx.x;
    float invN = 1.f / (float)N;
    float mn = st[c] * invN;
    float vr = fmaxf(st[128 + c] * invN - mn * mn, 0.f);
    float s = g[c] * rsqrtf(vr + BN_EPS);
    sc[c] = s;
    sh[c] = be[c] - mn * s;
  }
  __syncthreads();
  int idx = blockIdx.x * 256 + threadIdx.x;
  if (idx >= N * 4) return;
  int n = idx >> 2, c = idx & 3;
  const float* ur = u + (size_t)n * 128;
  float acc = bc2[c];
#pragma unroll 8
  for (int k = 0; k < 128; ++k) {
    float v = fmaxf(fmaf(ur[k], sc[k], sh[k]), 0.f);
    acc = fmaf(v, Wl[k * 4 + c], acc);
  }
  out[idx] = acc;
}

extern "C" void kernel_launch(void* const* d_in, const int* in_sizes, int n_in,
                              void* d_out, int out_size, void* d_ws, size_t ws_size,
                              hipStream_t stream) {
  const float* xs   = (const float*)d_in[0];
  const int*   esrc = (const int*)d_in[1];
  const int*   edst = (const int*)d_in[2];
  const float* ew   = (const float*)d_in[3];
  const float* W1   = (const float*)d_in[4];
  const float* g1   = (const float*)d_in[6];
  const float* be1  = (const float*)d_in[7];
  const float* W2   = (const float*)d_in[8];
  const float* g2   = (const float*)d_in[10];
  const float* be2  = (const float*)d_in[11];
  const float* gW   = (const float*)d_in[12];
  const float* gg   = (const float*)d_in[14];
  const float* gbe  = (const float*)d_in[15];
  const float* Wp   = (const float*)d_in[16];
  const float* gp   = (const float*)d_in[18];
  const float* bep  = (const float*)d_in[19];
  const float* Wih  = (const float*)d_in[20];
  const float* Whh  = (const float*)d_in[21];
  const float* bih  = (const float*)d_in[22];
  const float* bhh  = (const float*)d_in[23];
  const float* Wc1  = (const float*)d_in[24];
  const float* gc   = (const float*)d_in[26];
  const float* bec  = (const float*)d_in[27];
  const float* Wc2  = (const float*)d_in[28];
  const float* bc2  = (const float*)d_in[29];
  float* out = (float*)d_out;

  const int T = 8;
  const int N = in_sizes[0] / (T * 32);
  const int E = in_sizes[1] / T;
  const int TE = T * E, TN = T * N, N1 = N + 1;

  // ---- workspace layout (bytes) ----
  size_t off = 0;
  auto alloc = [&](size_t bytes) { size_t o = off; off += (bytes + 255) & ~(size_t)255; return o; };
  char* base = (char*)d_ws;
  size_t oH      = alloc((size_t)T * N * 64 * 2);   // H bf16 (normalized)
  size_t oEpk    = alloc((size_t)TE * 8);           // packed (src, w/norm)
  size_t oRp     = alloc((size_t)T * N1 * 4);       // rowptr
  size_t oDinv   = alloc((size_t)TN * 4);           // dinv
  size_t oStats  = alloc((size_t)49 * 256 * 4);     // stats slots
  size_t oBsum   = alloc((size_t)T * 256 * 4);      // scan block sums
  size_t oWf     = alloc((size_t)70000 * 2);        // prebuilt weight fragments
  size_t oArena  = alloc((size_t)64 * 1024 * 1024); // phase-shared arena
  if (ws_size < off) return;

  ushort* H     = (ushort*)(base + oH);
  int2*   epk   = (int2*)(base + oEpk);
  int*    rowptr= (int*)(base + oRp);
  float*  dinv  = (float*)(base + oDinv);
  float*  statsA= (float*)(base + oStats);
  int*    bsum  = (int*)(base + oBsum);
  ushort* wfA   = (ushort*)(base + oWf);
  char*   arena = base + oArena;

  // weight fragment offsets (ushort elements)
  ushort* W1f  = wfA;               // 32*128  = 4096
  ushort* W2f  = W1f + 4096;        // 128*64  = 8192
  ushort* gW0f = W2f + 8192;        // 64*64   = 4096
  ushort* gW1f = gW0f + 4096;
  ushort* gW2f = gW1f + 4096;
  ushort* Wpf  = gW2f + 4096;       // 64*64
  ushort* Wihf = Wpf + 4096;        // 64*192  = 12288
  ushort* Whhf = Wihf + 12288;
  ushort* Wc1f = Whhf + 12288;      // 64*128  = 8192  (total 61440)

  // prep-phase arena views
  int* cnt  = (int*)arena;                         // [T*N]
  int* incl = cnt + TN;                            // [T*N]
  int* rank = incl + TN;                           // [T*E]
  // encoder-phase arena views
  float*  y1f  = (float*)arena;                    // [N,128] fp32 raw (also praw)
  float*  hbf  = y1f + (size_t)N * 128;            // [N,64]  fp32 raw
  ushort* hcur = (ushort*)(hbf + (size_t)N * 64);  // [N,64]  bf16 normalized
  ushort* xwb  = hcur + (size_t)N * 64;            // [N,64]  bf16 gather table
  float*  ag   = (float*)(xwb + (size_t)N * 64);   // [N,64]  fp32 raw agg
  // gru/cls-phase arena views
  ushort* gi = (ushort*)arena;                     // [N,192] bf16 ([0,19.2MB))
  ushort* hA = (ushort*)(arena + (size_t)40 * 1024 * 1024);  // [N,64]
  ushort* hB = hA + (size_t)N * 64;
  float*  uf = (float*)arena;                      // [N,128] fp32 ([0,25.6MB), gi dead)

  const int nb = CDIV(N, 256);

#define SLOT(t, j) (statsA + ((size_t)(t) * 6 + (j)) * 256)

  hipMemsetAsync(statsA, 0, (size_t)49 * 256 * 4, stream);
  hipMemsetAsync(cnt, 0, (size_t)TN * 4, stream);

  // ---- weight fragment prep (once per launch, 9 tiny blocks) ----
  wprep_k<32, 128, false><<<1, 256, 0, stream>>>(W1, W1f);
  wprep_k<128, 64, false><<<1, 256, 0, stream>>>(W2, W2f);
  wprep_k<64, 64, false><<<1, 256, 0, stream>>>(gW, gW0f);
  wprep_k<64, 64, false><<<1, 256, 0, stream>>>(gW + 4096, gW1f);
  wprep_k<64, 64, false><<<1, 256, 0, stream>>>(gW + 8192, gW2f);
  wprep_k<64, 64, false><<<1, 256, 0, stream>>>(Wp, Wpf);
  wprep_k<64, 192, true><<<1, 256, 0, stream>>>(Wih, Wihf);
  wprep_k<64, 192, true><<<1, 256, 0, stream>>>(Whh, Whhf);

  // ================= batched graph prep (all T, XCD-partitioned) =================
  const int nbe = CDIV(E, 256);   // edge chunks per t
  hist_k<<<8 * nbe, 256, 0, stream>>>(edst, cnt, rank, N, E);
  scan1_k<<<dim3(nb, T), 256, 0, stream>>>(cnt, incl, bsum, N);
  scan2_k<<<dim3(1, T), 256, 0, stream>>>(bsum, nb);
  scan3_k<<<dim3(nb, T), 256, 0, stream>>>(incl, cnt, bsum, rowptr, N, E);
  scat_k<<<8 * nbe, 256, 0, stream>>>(esrc, edst, ew, rank, rowptr, epk, N1, E);
  deg_k<<<8 * nb, 256, 0, stream>>>(epk, rowptr, dinv, N, N1, E);
  norm_k<<<8 * nb, 256, 0, stream>>>(epk, rowptr, dinv, N, N1, E);
  wprep_k<64, 128, false><<<1, 256, 0, stream>>>(Wc1, Wc1f);

  const int gemmGrid = CDIV(N, 128);
  const float* ncf = nullptr;   // const float* null
  float* nmf = nullptr;         // float* null (oStat)
  ushort* nus = nullptr;        // ushort* null
  const ushort* ncus = nullptr; // const ushort* null

  // ================= encoder over T timesteps =================
  for (int t = 0; t < T; ++t) {
    const float* xt = xs + (size_t)t * N * 32;
    const int* rpT = rowptr + (size_t)t * N1;
    const int2* epkT = epk + (size_t)t * E;
    const float* dinvT = dinv + (size_t)t * N;

    // MLP1: y1f(fp32 raw) = xt @ W1, stats0
    gemm2<32, 128, 1, true, true, false, false><<<gemmGrid, 256, 0, stream>>>(
        xt, ncf, W1f, y1f, nus, ncf, ncf, ncf, SLOT(t, 0),
        ncus, ncf, ncf, nus, N);
    // MLP2: hbf(fp32 raw) = BNReLU(y1f) @ W2, stats1
    gemm2<128, 64, 2, true, true, false, false><<<gemmGrid, 256, 0, stream>>>(
        y1f, ncf, W2f, hbf, nus, SLOT(t, 0), g1, be1, SLOT(t, 1),
        ncus, ncf, ncf, nus, N);
    // GCN0: A = BNReLU(hbf) [-> side hcur], out xwb bf16
    gemm2<64, 64, 2, false, false, true, false><<<gemmGrid, 256, 0, stream>>>(
        hbf, ncf, gW0f, xwb, hcur, SLOT(t, 1), g2, be2, nmf,
        ncus, ncf, ncf, nus, N);
    agg_k<<<2048, 256, 0, stream>>>(xwb, dinvT, rpT, epkT, ag, SLOT(t, 2), N);
    // GCN1: A = hcur + ReLU(BN(ag)) [-> side hcur], out xwb
    gemm2<64, 64, 3, false, false, true, false><<<gemmGrid, 256, 0, stream>>>(
        hcur, ag, gW1f, xwb, hcur, SLOT(t, 2), gg, gbe, nmf,
        ncus, ncf, ncf, nus, N);
    agg_k<<<2048, 256, 0, stream>>>(xwb, dinvT, rpT, epkT, ag, SLOT(t, 3), N);
    // GCN2
    gemm2<64, 64, 3, false, false, true, false><<<gemmGrid, 256, 0, stream>>>(
        hcur, ag, gW2f, xwb, hcur, SLOT(t, 3), gg + 64, gbe + 64, nmf,
        ncus, ncf, ncf, nus, N);
    agg_k<<<2048, 256, 0, stream>>>(xwb, dinvT, rpT, epkT, ag, SLOT(t, 4), N);
    // POST: A = hcur + ReLU(BN(ag)), out praw(y1f) fp32 + stats5
    gemm2<64, 64, 3, true, true, false, false><<<gemmGrid, 256, 0, stream>>>(
        hcur, ag, Wpf, y1f, nus, SLOT(t, 4), gg + 128, gbe + 128, SLOT(t, 5),
        ncus, ncf, ncf, nus, N);
    bnbf_k<<<CDIV(N * 16, 256), 256, 0, stream>>>(y1f, H + (size_t)t * N * 64, SLOT(t, 5), gp, bep, N, 64);
  }

  // ================= GRU over T steps =================
  hipMemsetAsync(hA, 0, (size_t)N * 64 * 2, stream);
  ushort* hprev = hA;
  ushort* hnext = hB;
  for (int t = 0; t < T; ++t) {
    // gi = H[t] @ Wih^T  (bf16 out, bias folded into gate)
    gemm2<64, 192, 0, false, false, false, false><<<gemmGrid, 256, 0, stream>>>(
        H + (size_t)t * N * 64, ncf, Wihf, gi, nus, ncf, ncf, ncf, nmf,
        ncus, ncf, ncf, nus, N);
    // gh = hprev @ Whh^T + fused GRU gate -> hnext
    gemm2<64, 192, 0, false, false, false, true><<<gemmGrid, 256, 0, stream>>>(
        hprev, ncf, Whhf, (void*)nullptr, nus, ncf, ncf, ncf, nmf,
        gi, bih, bhh, hnext, N);
    ushort* tmp = hprev; hprev = hnext; hnext = tmp;
  }
  // after 8 steps hprev == hA (arena+40MB; uf occupies [0,25.6MB) - no overlap)

  // ================= classifier =================
  gemm2<64, 128, 0, true, true, false, false><<<gemmGrid, 256, 0, stream>>>(
      hprev, ncf, Wc1f, uf, nus, ncf, ncf, ncf, statsA + 48 * 256,
      ncus, ncf, ncf, nus, N);
  final_k<<<CDIV(N * 4, 256), 256, 0, stream>>>(uf, statsA + 48 * 256, gc, bec, Wc2, bc2, out, N);
}